// Round 1
// baseline (2389.453 us; speedup 1.0000x reference)
//
#include <hip/hip_runtime.h>
#include <math.h>

// StrategistGNN forward on MI355X. Round 0: correctness-first f32 implementation.
// N=4096 nodes, E=65536 edges, H=128, 4 heads x 32, L=4 GAT layers, B=1.
// ws usage ~22.6 MB (see layout in kernel_launch).

#define NN 4096
#define EE 65536
#define HH 128
#define NHEADS 4
#define HDIM 32
#define NLAYERS 4
#define NFEAT 16
#define GFEAT 8
#define EFEAT 4
#define KS 4   // key-splits for global attention

__device__ __forceinline__ float gelu_f(float x){
  return 0.5f * x * (1.0f + erff(x * 0.7071067811865475f));
}
__device__ __forceinline__ float sigm(float x){ return 1.0f / (1.0f + expf(-x)); }
__device__ __forceinline__ float softplus_f(float x){ return x > 20.0f ? x : log1pf(expf(x)); }

// block-wide sum over 128 threads; red is a shared float[128]
__device__ __forceinline__ float block_sum128(float v, float* red){
  int j = threadIdx.x;
  red[j] = v; __syncthreads();
  for (int s = 64; s > 0; s >>= 1){
    if (j < s) red[j] += red[j + s];
    __syncthreads();
  }
  float r = red[0];
  __syncthreads();
  return r;
}

// ---------------- CSR build (incoming edges per dst) ----------------
__global__ void k_hist(const int* __restrict__ ei, int* __restrict__ cnt){
  int e = blockIdx.x * 256 + threadIdx.x;
  if (e < EE) atomicAdd(&cnt[ei[EE + e]], 1);
}

__global__ void k_scan(const int* __restrict__ cnt, int* __restrict__ off, int* __restrict__ cur){
  __shared__ int part[256];
  int t = threadIdx.x;
  int local[16];
  int s = 0;
  #pragma unroll
  for (int i = 0; i < 16; i++){ local[i] = s; s += cnt[t * 16 + i]; }
  part[t] = s; __syncthreads();
  for (int o = 1; o < 256; o <<= 1){
    int v = (t >= o) ? part[t - o] : 0;
    __syncthreads();
    part[t] += v;
    __syncthreads();
  }
  int base = part[t] - s;   // exclusive prefix of this thread's chunk
  #pragma unroll
  for (int i = 0; i < 16; i++){ int o = base + local[i]; off[t * 16 + i] = o; cur[t * 16 + i] = o; }
  if (t == 255) off[NN] = part[255];
}

__global__ void k_scatter(const int* __restrict__ ei, int* __restrict__ cur, int* __restrict__ eid){
  int e = blockIdx.x * 256 + threadIdx.x;
  if (e < EE){
    int d = ei[EE + e];
    int p = atomicAdd(&cur[d], 1);
    eid[p] = e;
  }
}

// ---------------- encoders ----------------
__global__ void k_ue(const float* __restrict__ u, const float* __restrict__ W,
                     const float* __restrict__ b, const float* __restrict__ g,
                     const float* __restrict__ be, float* __restrict__ ue){
  __shared__ float red[128];
  __shared__ float us[GFEAT];
  int j = threadIdx.x;
  if (j < GFEAT) us[j] = u[j];
  __syncthreads();
  float acc = b[j];
  #pragma unroll
  for (int k = 0; k < GFEAT; k++) acc += us[k] * W[j * GFEAT + k];
  float mu = block_sum128(acc, red) * (1.0f / HH);
  float d = acc - mu;
  float var = block_sum128(d * d, red) * (1.0f / HH);
  ue[j] = gelu_f(d * rsqrtf(var + 1e-5f) * g[j] + be[j]);
}

__global__ void k_node_enc(const float* __restrict__ x, const float* __restrict__ tf,
                           const float* __restrict__ W, const float* __restrict__ b,
                           const float* __restrict__ g, const float* __restrict__ be,
                           const float* __restrict__ ue, float* __restrict__ h){
  __shared__ float red[128];
  __shared__ float xs[NFEAT + 1];
  int n = blockIdx.x, j = threadIdx.x;
  if (j < NFEAT) xs[j] = x[n * NFEAT + j];
  if (j == NFEAT) xs[NFEAT] = tf[0];
  __syncthreads();
  float acc = b[j];
  #pragma unroll
  for (int k = 0; k < NFEAT + 1; k++) acc += xs[k] * W[j * (NFEAT + 1) + k];
  float mu = block_sum128(acc, red) * (1.0f / HH);
  float d = acc - mu;
  float var = block_sum128(d * d, red) * (1.0f / HH);
  h[n * HH + j] = gelu_f(d * rsqrtf(var + 1e-5f) * g[j] + be[j]) + ue[j];
}

// ---------------- GRU ----------------
__global__ void k_gru(const float* __restrict__ tiles, const float* __restrict__ Wih,
                      const float* __restrict__ bih, const float* __restrict__ Whh,
                      const float* __restrict__ bhh, float* __restrict__ h,
                      float* __restrict__ out_tiles){
  __shared__ float hs[HH], ts[HH];
  int n = blockIdx.x, j = threadIdx.x;
  hs[j] = h[n * HH + j]; ts[j] = tiles[n * HH + j];
  __syncthreads();
  float ir = bih[j], iz = bih[HH + j], in_ = bih[2 * HH + j];
  float hr = bhh[j], hz = bhh[HH + j], hn = bhh[2 * HH + j];
  const float* wr = &Wih[j * HH];            const float* vr = &Whh[j * HH];
  const float* wz = &Wih[(HH + j) * HH];     const float* vz = &Whh[(HH + j) * HH];
  const float* wn = &Wih[(2 * HH + j) * HH]; const float* vn = &Whh[(2 * HH + j) * HH];
  #pragma unroll 4
  for (int k = 0; k < HH; k++){
    float hv = hs[k], tv = ts[k];
    ir += hv * wr[k]; iz += hv * wz[k]; in_ += hv * wn[k];
    hr += tv * vr[k]; hz += tv * vz[k]; hn += tv * vn[k];
  }
  float r = sigm(ir + hr), z = sigm(iz + hz);
  float nn2 = tanhf(in_ + r * hn);
  float hnew = (1.0f - z) * nn2 + z * ts[j];
  h[n * HH + j] = hnew;
  out_tiles[n * HH + j] = hnew;
}

// ---------------- GATv2 layer pieces ----------------
__global__ void k_xlxr(const float* __restrict__ h, const float* __restrict__ Wl,
                       const float* __restrict__ bl, const float* __restrict__ Wr,
                       const float* __restrict__ br, float* __restrict__ xl, float* __restrict__ xr){
  __shared__ float hs[HH];
  int n = blockIdx.x, j = threadIdx.x;
  hs[j] = h[n * HH + j];
  __syncthreads();
  float al = bl[j], ar = br[j];
  const float* wl = &Wl[j * HH]; const float* wr = &Wr[j * HH];
  #pragma unroll 4
  for (int k = 0; k < HH; k++){ float hv = hs[k]; al += hv * wl[k]; ar += hv * wr[k]; }
  xl[n * HH + j] = al; xr[n * HH + j] = ar;
}

// per-edge attention logits -> exp(score); max-subtraction skipped (scores are O(1),
// softmax is shift-invariant, empty segments produce agg=0 either way)
__global__ void k_score(const int* __restrict__ ei, const float* __restrict__ ea,
                        const float* __restrict__ xl, const float* __restrict__ xr,
                        const float* __restrict__ We, const float* __restrict__ att,
                        float* __restrict__ ex){
  int e = blockIdx.x * 256 + threadIdx.x;
  if (e >= EE) return;
  int s = ei[e], d = ei[EE + e];
  float a0 = ea[e * 4], a1 = ea[e * 4 + 1], a2 = ea[e * 4 + 2], a3 = ea[e * 4 + 3];
  const float* xls = &xl[s * HH];
  const float* xrd = &xr[d * HH];
  #pragma unroll
  for (int hh = 0; hh < NHEADS; hh++){
    float sc = 0.0f;
    #pragma unroll
    for (int dd = 0; dd < HDIM; dd++){
      int j = hh * HDIM + dd;
      float eev = a0 * We[j * 4] + a1 * We[j * 4 + 1] + a2 * We[j * 4 + 2] + a3 * We[j * 4 + 3];
      float v = xls[j] + xrd[j] + eev;
      v = v > 0.0f ? v : 0.2f * v;
      sc += v * att[j];
    }
    ex[e * 4 + hh] = expf(sc);
  }
}

// gather incoming edges per node, softmax-normalize, aggregate xl[src], add bias, residual+LN
__global__ void k_aggln(const float* __restrict__ xl, const float* __restrict__ ex,
                        const int* __restrict__ off, const int* __restrict__ eid,
                        const int* __restrict__ ei,
                        const float* __restrict__ bias, const float* __restrict__ g,
                        const float* __restrict__ b, float* __restrict__ h){
  __shared__ float red[128];
  __shared__ float den[NHEADS];
  int n = blockIdx.x, j = threadIdx.x;
  int p0 = off[n], p1 = off[n + 1];
  if (j < NHEADS){
    float s = 0.0f;
    for (int p = p0; p < p1; p++) s += ex[eid[p] * 4 + j];
    den[j] = s;
  }
  __syncthreads();
  int hh = j >> 5;
  float dinv = 1.0f / (den[hh] + 1e-16f);
  float agg = 0.0f;
  for (int p = p0; p < p1; p++){
    int e = eid[p];
    int s = ei[e];
    agg += ex[e * 4 + hh] * xl[s * HH + j];
  }
  agg *= dinv;
  float val = h[n * HH + j] + agg + bias[j];
  float mu = block_sum128(val, red) * (1.0f / HH);
  float d2 = val - mu;
  float var = block_sum128(d2 * d2, red) * (1.0f / HH);
  h[n * HH + j] = d2 * rsqrtf(var + 1e-5f) * g[j] + b[j];
}

// ---------------- global attention ----------------
__global__ void k_qkv(const float* __restrict__ h, const float* __restrict__ Win,
                      const float* __restrict__ bin, float* __restrict__ q,
                      float* __restrict__ kk, float* __restrict__ v){
  __shared__ float hs[HH];
  int n = blockIdx.x, j = threadIdx.x;
  hs[j] = h[n * HH + j];
  __syncthreads();
  float aq = bin[j], ak = bin[HH + j], av = bin[2 * HH + j];
  const float* wq = &Win[j * HH];
  const float* wk = &Win[(HH + j) * HH];
  const float* wv = &Win[(2 * HH + j) * HH];
  #pragma unroll 4
  for (int k = 0; k < HH; k++){ float hv = hs[k]; aq += hv * wq[k]; ak += hv * wk[k]; av += hv * wv[k]; }
  q[n * HH + j] = aq; kk[n * HH + j] = ak; v[n * HH + j] = av;
}

// one block: 64 queries x 1 head x 1 key-split (1024 keys). No max-subtraction (scores O(1)).
__global__ void k_attn_part(const float* __restrict__ q, const float* __restrict__ kk,
                            const float* __restrict__ v, float* __restrict__ pden,
                            float* __restrict__ pacc){
  __shared__ float ksh[64][36];   // pad 32->36: rows stay 16B-aligned, writes conflict-free
  __shared__ float vsh[64][36];
  int t = threadIdx.x;            // 64
  int qt = blockIdx.x, hh = blockIdx.y, ks = blockIdx.z;
  int qn = qt * 64 + t;
  float qreg[HDIM], acc[HDIM];
  #pragma unroll
  for (int d = 0; d < HDIM; d++){ qreg[d] = q[qn * HH + hh * HDIM + d]; acc[d] = 0.0f; }
  float den = 0.0f;
  const float scale = 0.17677669529663687f;  // 1/sqrt(32)
  for (int c = ks * (NN / KS); c < (ks + 1) * (NN / KS); c += 64){
    float tmpk[HDIM], tmpv[HDIM];
    #pragma unroll
    for (int d = 0; d < HDIM; d++){
      tmpk[d] = kk[(c + t) * HH + hh * HDIM + d];
      tmpv[d] = v [(c + t) * HH + hh * HDIM + d];
    }
    __syncthreads();   // previous chunk's consumers done before overwrite
    #pragma unroll
    for (int d = 0; d < HDIM; d++){ ksh[t][d] = tmpk[d]; vsh[t][d] = tmpv[d]; }
    __syncthreads();
    for (int jj = 0; jj < 64; jj++){
      float s = 0.0f;
      #pragma unroll
      for (int d = 0; d < HDIM; d++) s += qreg[d] * ksh[jj][d];
      float e2 = expf(s * scale);
      den += e2;
      #pragma unroll
      for (int d = 0; d < HDIM; d++) acc[d] += e2 * vsh[jj][d];
    }
  }
  int pi = (qn * NHEADS + hh) * KS + ks;
  pden[pi] = den;
  #pragma unroll
  for (int d = 0; d < HDIM; d++) pacc[pi * HDIM + d] = acc[d];
}

__global__ void k_attn_out(const float* __restrict__ pden, const float* __restrict__ pacc,
                           const float* __restrict__ Wout, const float* __restrict__ bout,
                           const float* __restrict__ g, const float* __restrict__ b,
                           float* __restrict__ h){
  __shared__ float red[128];
  __shared__ float aos[HH];
  int n = blockIdx.x, j = threadIdx.x;
  int hh = j >> 5, d = j & 31;
  float ds = 0.0f, as = 0.0f;
  #pragma unroll
  for (int ks = 0; ks < KS; ks++){
    int pi = (n * NHEADS + hh) * KS + ks;
    ds += pden[pi];
    as += pacc[pi * HDIM + d];
  }
  aos[j] = as / ds;
  __syncthreads();
  float acc = bout[j];
  const float* w = &Wout[j * HH];
  #pragma unroll 4
  for (int k = 0; k < HH; k++) acc += aos[k] * w[k];
  float val = h[n * HH + j] + acc;
  float mu = block_sum128(val, red) * (1.0f / HH);
  float dd = val - mu;
  float var = block_sum128(dd * dd, red) * (1.0f / HH);
  h[n * HH + j] = dd * rsqrtf(var + 1e-5f) * g[j] + b[j];
}

// ---------------- edge heads ----------------
// 8 edges per 128-thread block; 16 threads per edge, 8 hidden dims each.
__global__ void k_edge_heads(const float* __restrict__ h, const int* __restrict__ ei,
                             const float* __restrict__ ea,
                             const float* __restrict__ mvW1, const float* __restrict__ mvb1,
                             const float* __restrict__ mvW2, const float* __restrict__ mvb2,
                             const float* __restrict__ frW1, const float* __restrict__ frb1,
                             const float* __restrict__ frW2, const float* __restrict__ frb2,
                             float* __restrict__ out){
  __shared__ float eemb[8][260];
  __shared__ float am[8], a0[8], a1[8];
  int t = threadIdx.x;
  int e0 = blockIdx.x * 8;
  for (int idx = t; idx < 8 * 260; idx += 128){
    int el = idx / 260, k2 = idx - el * 260;
    int e = e0 + el;
    float vv;
    if (k2 < HH)            vv = h[ei[e] * HH + k2];
    else if (k2 < 2 * HH)   vv = h[ei[EE + e] * HH + (k2 - HH)];
    else                    vv = ea[e * 4 + (k2 - 2 * HH)];
    eemb[el][k2] = vv;
  }
  if (t < 8){ am[t] = 0.0f; a0[t] = 0.0f; a1[t] = 0.0f; }
  __syncthreads();
  int el = t >> 4, g2 = t & 15;
  const float* em = eemb[el];
  float sm = 0.0f, s0 = 0.0f, s1 = 0.0f;
  for (int i = 0; i < 8; i++){
    int j = g2 + 16 * i;
    const float* wm = &mvW1[j * 260];
    const float* wf = &frW1[j * 260];
    float pm = mvb1[j], pf = frb1[j];
    #pragma unroll 4
    for (int k2 = 0; k2 < 260; k2++){ float xv = em[k2]; pm += wm[k2] * xv; pf += wf[k2] * xv; }
    float hm = gelu_f(pm), hf = gelu_f(pf);
    sm += hm * mvW2[j];
    s0 += hf * frW2[j];
    s1 += hf * frW2[HH + j];
  }
  atomicAdd(&am[el], sm); atomicAdd(&a0[el], s0); atomicAdd(&a1[el], s1);
  __syncthreads();
  if (t < 8){
    int e = e0 + t;
    out[e]          = am[t] + mvb2[0];
    out[EE + e]     = softplus_f(a0[t] + frb2[0]) + 1e-4f;
    out[2 * EE + e] = softplus_f(a1[t] + frb2[1]) + 1e-4f;
  }
}

// ---------------- value head ----------------
__global__ void k_pool(const float* __restrict__ h, const unsigned char* __restrict__ mask,
                       float* __restrict__ gsum, float* __restrict__ msum, float* __restrict__ mcnt){
  int bb = blockIdx.x, j = threadIdx.x;
  float ga = 0.0f, ma = 0.0f;
  int n0 = bb * 32;
  for (int i = 0; i < 32; i++){
    int n = n0 + i;
    float v = h[n * HH + j];
    ga += v;
    if (mask[n]) ma += v;
  }
  atomicAdd(&gsum[j], ga);
  atomicAdd(&msum[j], ma);
  if (j == 0){
    float c = 0.0f;
    for (int i = 0; i < 32; i++) c += mask[n0 + i] ? 1.0f : 0.0f;
    atomicAdd(mcnt, c);
  }
}

__global__ void k_value(const float* __restrict__ gsum, const float* __restrict__ msum,
                        const float* __restrict__ mcnt,
                        const float* __restrict__ W1, const float* __restrict__ b1,
                        const float* __restrict__ W2, const float* __restrict__ b2,
                        float* __restrict__ out_val){
  __shared__ float red[128];
  __shared__ float vin[256];
  int j = threadIdx.x;
  float gp = gsum[j] * (1.0f / NN);
  float as = msum[j] * (1.0f / NN);
  float ac = fmaxf(mcnt[0] * (1.0f / NN), 1e-6f);
  vin[j] = gp; vin[HH + j] = as / ac;
  __syncthreads();
  float acc = b1[j];
  const float* w = &W1[j * 256];
  #pragma unroll 4
  for (int k = 0; k < 256; k++) acc += vin[k] * w[k];
  float hv = gelu_f(acc) * W2[j];
  float s = block_sum128(hv, red);
  if (j == 0) out_val[0] = s + b2[0];
}

extern "C" void kernel_launch(void* const* d_in, const int* in_sizes, int n_in,
                              void* d_out, int out_size, void* d_ws, size_t ws_size,
                              hipStream_t stream){
  (void)in_sizes; (void)n_in; (void)out_size; (void)ws_size;
  const float* x        = (const float*)d_in[0];
  const int*   ei       = (const int*)d_in[1];
  const float* ea       = (const float*)d_in[2];
  const float* u        = (const float*)d_in[3];
  const unsigned char* mask = (const unsigned char*)d_in[4];  // numpy bool = 1 byte
  const float* tiles    = (const float*)d_in[5];
  // d_in[6] = batch (all zeros, B=1) -- unused
  const float* tf       = (const float*)d_in[7];
  const float* ne_W  = (const float*)d_in[8];
  const float* ne_b  = (const float*)d_in[9];
  const float* ne_g  = (const float*)d_in[10];
  const float* ne_be = (const float*)d_in[11];
  const float* ge_W  = (const float*)d_in[12];
  const float* ge_b  = (const float*)d_in[13];
  const float* ge_g  = (const float*)d_in[14];
  const float* ge_be = (const float*)d_in[15];
  const float* gru_Wih = (const float*)d_in[16];
  const float* gru_bih = (const float*)d_in[17];
  const float* gru_Whh = (const float*)d_in[18];
  const float* gru_bhh = (const float*)d_in[19];
  const float* gat_Wl  = (const float*)d_in[20];
  const float* gat_bl  = (const float*)d_in[21];
  const float* gat_Wr  = (const float*)d_in[22];
  const float* gat_br  = (const float*)d_in[23];
  const float* gat_We  = (const float*)d_in[24];
  const float* gat_att = (const float*)d_in[25];
  const float* gat_bias= (const float*)d_in[26];
  const float* ln_g    = (const float*)d_in[27];
  const float* ln_b    = (const float*)d_in[28];
  const float* attn_Win = (const float*)d_in[29];
  const float* attn_bin = (const float*)d_in[30];
  const float* attn_Wout= (const float*)d_in[31];
  const float* attn_bout= (const float*)d_in[32];
  const float* lng_g    = (const float*)d_in[33];
  const float* lng_b    = (const float*)d_in[34];
  const float* mv_W1 = (const float*)d_in[35];
  const float* mv_b1 = (const float*)d_in[36];
  const float* mv_W2 = (const float*)d_in[37];
  const float* mv_b2 = (const float*)d_in[38];
  const float* fr_W1 = (const float*)d_in[39];
  const float* fr_b1 = (const float*)d_in[40];
  const float* fr_W2 = (const float*)d_in[41];
  const float* fr_b2 = (const float*)d_in[42];
  const float* vl_W1 = (const float*)d_in[43];
  const float* vl_b1 = (const float*)d_in[44];
  const float* vl_W2 = (const float*)d_in[45];
  const float* vl_b2 = (const float*)d_in[46];

  // ---- workspace layout (float elements) ----
  float* ws   = (float*)d_ws;
  float* h    = ws;                  // 524288
  float* xl   = ws + 524288;         // 524288
  float* xr   = ws + 1048576;        // 524288
  float* ex   = ws + 1572864;        // 262144
  float* q    = ws + 1835008;        // 524288
  float* kbuf = ws + 2359296;        // 524288
  float* vbuf = ws + 2883584;        // 524288
  float* pden = ws + 3407872;        // 65536
  float* pacc = ws + 3473408;        // 2097152
  float* ue   = ws + 5570560;        // 128
  float* gsum = ws + 5570688;        // 128
  float* msum = gsum + 128;          // 128
  float* mcnt = gsum + 256;          // 1
  int*   cnt  = (int*)(ws + 5571072); // 4096
  int*   off  = cnt + NN;             // 4097
  int*   cur  = off + NN + 1;         // 4096
  int*   eid  = cur + NN;             // 65536
  // total ~5.65M elements = 22.6 MB

  float* out       = (float*)d_out;
  float* out_val   = out + 3 * EE;       // [196608]
  float* out_tiles = out + 3 * EE + 1;   // [196609 ..)

  // CSR of incoming edges
  hipMemsetAsync(cnt, 0, NN * sizeof(int), stream);
  k_hist   <<<EE / 256, 256, 0, stream>>>(ei, cnt);
  k_scan   <<<1, 256, 0, stream>>>(cnt, off, cur);
  k_scatter<<<EE / 256, 256, 0, stream>>>(ei, cur, eid);

  // encoders + GRU
  k_ue      <<<1, 128, 0, stream>>>(u, ge_W, ge_b, ge_g, ge_be, ue);
  k_node_enc<<<NN, 128, 0, stream>>>(x, tf, ne_W, ne_b, ne_g, ne_be, ue, h);
  k_gru     <<<NN, 128, 0, stream>>>(tiles, gru_Wih, gru_bih, gru_Whh, gru_bhh, h, out_tiles);

  // GATv2 stack
  for (int l = 0; l < NLAYERS; l++){
    k_xlxr <<<NN, 128, 0, stream>>>(h, gat_Wl + l * HH * HH, gat_bl + l * HH,
                                    gat_Wr + l * HH * HH, gat_br + l * HH, xl, xr);
    k_score<<<EE / 256, 256, 0, stream>>>(ei, ea, xl, xr,
                                          gat_We + l * HH * EFEAT,
                                          gat_att + l * NHEADS * HDIM, ex);
    k_aggln<<<NN, 128, 0, stream>>>(xl, ex, off, eid, ei,
                                    gat_bias + l * HH, ln_g + l * HH, ln_b + l * HH, h);
  }

  // global attention
  k_qkv<<<NN, 128, 0, stream>>>(h, attn_Win, attn_bin, q, kbuf, vbuf);
  dim3 gattn(NN / 64, NHEADS, KS);
  k_attn_part<<<gattn, 64, 0, stream>>>(q, kbuf, vbuf, pden, pacc);
  k_attn_out <<<NN, 128, 0, stream>>>(pden, pacc, attn_Wout, attn_bout, lng_g, lng_b, h);

  // edge heads
  k_edge_heads<<<EE / 8, 128, 0, stream>>>(h, ei, ea, mv_W1, mv_b1, mv_W2, mv_b2,
                                           fr_W1, fr_b1, fr_W2, fr_b2, out);

  // value head
  hipMemsetAsync(gsum, 0, 257 * sizeof(float), stream);
  k_pool <<<128, 128, 0, stream>>>(h, mask, gsum, msum, mcnt);
  k_value<<<1, 128, 0, stream>>>(gsum, msum, mcnt, vl_W1, vl_b1, vl_W2, vl_b2, out_val);
}

// Round 2
// 1643.180 us; speedup vs baseline: 1.4542x; 1.4542x over previous
//
#include <hip/hip_runtime.h>
#include <math.h>

// StrategistGNN forward on MI355X. Round 2: edge heads via bf16 MFMA GEMM.
// N=4096 nodes, E=65536 edges, H=128, 4 heads x 32, L=4 GAT layers, B=1.

#define NN 4096
#define EE 65536
#define HH 128
#define NHEADS 4
#define HDIM 32
#define NLAYERS 4
#define NFEAT 16
#define GFEAT 8
#define EFEAT 4
#define KS 4     // key-splits for global attention
#define KPAD 296 // padded K stride (bf16 elems) for edge-head GEMM; 288 used, 296 breaks bank aliasing

typedef short bf16x8 __attribute__((ext_vector_type(8)));   // 8 bf16 in 4 VGPRs (guide-verified type)
typedef float f32x4  __attribute__((ext_vector_type(4)));

__device__ __forceinline__ float gelu_f(float x){
  return 0.5f * x * (1.0f + erff(x * 0.7071067811865475f));
}
__device__ __forceinline__ float sigm(float x){ return 1.0f / (1.0f + expf(-x)); }
__device__ __forceinline__ float softplus_f(float x){ return x > 20.0f ? x : log1pf(expf(x)); }
__device__ __forceinline__ unsigned short f2bf(float x){
  unsigned u = __float_as_uint(x);
  unsigned r = (u + 0x7FFFu + ((u >> 16) & 1u)) >> 16;
  return (unsigned short)r;
}

// block-wide sum over 128 threads; red is a shared float[128]
__device__ __forceinline__ float block_sum128(float v, float* red){
  int j = threadIdx.x;
  red[j] = v; __syncthreads();
  for (int s = 64; s > 0; s >>= 1){
    if (j < s) red[j] += red[j + s];
    __syncthreads();
  }
  float r = red[0];
  __syncthreads();
  return r;
}

// ---------------- CSR build (incoming edges per dst) ----------------
__global__ void k_hist(const int* __restrict__ ei, int* __restrict__ cnt){
  int e = blockIdx.x * 256 + threadIdx.x;
  if (e < EE) atomicAdd(&cnt[ei[EE + e]], 1);
}

__global__ void k_scan(const int* __restrict__ cnt, int* __restrict__ off, int* __restrict__ cur){
  __shared__ int part[256];
  int t = threadIdx.x;
  int local[16];
  int s = 0;
  #pragma unroll
  for (int i = 0; i < 16; i++){ local[i] = s; s += cnt[t * 16 + i]; }
  part[t] = s; __syncthreads();
  for (int o = 1; o < 256; o <<= 1){
    int v = (t >= o) ? part[t - o] : 0;
    __syncthreads();
    part[t] += v;
    __syncthreads();
  }
  int base = part[t] - s;
  #pragma unroll
  for (int i = 0; i < 16; i++){ int o = base + local[i]; off[t * 16 + i] = o; cur[t * 16 + i] = o; }
  if (t == 255) off[NN] = part[255];
}

__global__ void k_scatter(const int* __restrict__ ei, int* __restrict__ cur, int* __restrict__ eid){
  int e = blockIdx.x * 256 + threadIdx.x;
  if (e < EE){
    int d = ei[EE + e];
    int p = atomicAdd(&cur[d], 1);
    eid[p] = e;
  }
}

// ---------------- encoders ----------------
__global__ void k_ue(const float* __restrict__ u, const float* __restrict__ W,
                     const float* __restrict__ b, const float* __restrict__ g,
                     const float* __restrict__ be, float* __restrict__ ue){
  __shared__ float red[128];
  __shared__ float us[GFEAT];
  int j = threadIdx.x;
  if (j < GFEAT) us[j] = u[j];
  __syncthreads();
  float acc = b[j];
  #pragma unroll
  for (int k = 0; k < GFEAT; k++) acc += us[k] * W[j * GFEAT + k];
  float mu = block_sum128(acc, red) * (1.0f / HH);
  float d = acc - mu;
  float var = block_sum128(d * d, red) * (1.0f / HH);
  ue[j] = gelu_f(d * rsqrtf(var + 1e-5f) * g[j] + be[j]);
}

__global__ void k_node_enc(const float* __restrict__ x, const float* __restrict__ tf,
                           const float* __restrict__ W, const float* __restrict__ b,
                           const float* __restrict__ g, const float* __restrict__ be,
                           const float* __restrict__ ue, float* __restrict__ h){
  __shared__ float red[128];
  __shared__ float xs[NFEAT + 1];
  int n = blockIdx.x, j = threadIdx.x;
  if (j < NFEAT) xs[j] = x[n * NFEAT + j];
  if (j == NFEAT) xs[NFEAT] = tf[0];
  __syncthreads();
  float acc = b[j];
  #pragma unroll
  for (int k = 0; k < NFEAT + 1; k++) acc += xs[k] * W[j * (NFEAT + 1) + k];
  float mu = block_sum128(acc, red) * (1.0f / HH);
  float d = acc - mu;
  float var = block_sum128(d * d, red) * (1.0f / HH);
  h[n * HH + j] = gelu_f(d * rsqrtf(var + 1e-5f) * g[j] + be[j]) + ue[j];
}

// ---------------- GRU ----------------
__global__ void k_gru(const float* __restrict__ tiles, const float* __restrict__ Wih,
                      const float* __restrict__ bih, const float* __restrict__ Whh,
                      const float* __restrict__ bhh, float* __restrict__ h,
                      float* __restrict__ out_tiles){
  __shared__ float hs[HH], ts[HH];
  int n = blockIdx.x, j = threadIdx.x;
  hs[j] = h[n * HH + j]; ts[j] = tiles[n * HH + j];
  __syncthreads();
  float ir = bih[j], iz = bih[HH + j], in_ = bih[2 * HH + j];
  float hr = bhh[j], hz = bhh[HH + j], hn = bhh[2 * HH + j];
  const float* wr = &Wih[j * HH];            const float* vr = &Whh[j * HH];
  const float* wz = &Wih[(HH + j) * HH];     const float* vz = &Whh[(HH + j) * HH];
  const float* wn = &Wih[(2 * HH + j) * HH]; const float* vn = &Whh[(2 * HH + j) * HH];
  #pragma unroll 4
  for (int k = 0; k < HH; k++){
    float hv = hs[k], tv = ts[k];
    ir += hv * wr[k]; iz += hv * wz[k]; in_ += hv * wn[k];
    hr += tv * vr[k]; hz += tv * vz[k]; hn += tv * vn[k];
  }
  float r = sigm(ir + hr), z = sigm(iz + hz);
  float nn2 = tanhf(in_ + r * hn);
  float hnew = (1.0f - z) * nn2 + z * ts[j];
  h[n * HH + j] = hnew;
  out_tiles[n * HH + j] = hnew;
}

// ---------------- GATv2 layer pieces ----------------
__global__ void k_xlxr(const float* __restrict__ h, const float* __restrict__ Wl,
                       const float* __restrict__ bl, const float* __restrict__ Wr,
                       const float* __restrict__ br, float* __restrict__ xl, float* __restrict__ xr){
  __shared__ float hs[HH];
  int n = blockIdx.x, j = threadIdx.x;
  hs[j] = h[n * HH + j];
  __syncthreads();
  float al = bl[j], ar = br[j];
  const float* wl = &Wl[j * HH]; const float* wr = &Wr[j * HH];
  #pragma unroll 4
  for (int k = 0; k < HH; k++){ float hv = hs[k]; al += hv * wl[k]; ar += hv * wr[k]; }
  xl[n * HH + j] = al; xr[n * HH + j] = ar;
}

// per-edge attention logits -> exp(score); max-subtraction skipped (scores O(1), softmax shift-invariant)
__global__ void k_score(const int* __restrict__ ei, const float* __restrict__ ea,
                        const float* __restrict__ xl, const float* __restrict__ xr,
                        const float* __restrict__ We, const float* __restrict__ att,
                        float* __restrict__ ex){
  int e = blockIdx.x * 256 + threadIdx.x;
  if (e >= EE) return;
  int s = ei[e], d = ei[EE + e];
  float a0 = ea[e * 4], a1 = ea[e * 4 + 1], a2 = ea[e * 4 + 2], a3 = ea[e * 4 + 3];
  const float* xls = &xl[s * HH];
  const float* xrd = &xr[d * HH];
  #pragma unroll
  for (int hh = 0; hh < NHEADS; hh++){
    float sc = 0.0f;
    #pragma unroll
    for (int dd = 0; dd < HDIM; dd++){
      int j = hh * HDIM + dd;
      float eev = a0 * We[j * 4] + a1 * We[j * 4 + 1] + a2 * We[j * 4 + 2] + a3 * We[j * 4 + 3];
      float v = xls[j] + xrd[j] + eev;
      v = v > 0.0f ? v : 0.2f * v;
      sc += v * att[j];
    }
    ex[e * 4 + hh] = expf(sc);
  }
}

__global__ void k_aggln(const float* __restrict__ xl, const float* __restrict__ ex,
                        const int* __restrict__ off, const int* __restrict__ eid,
                        const int* __restrict__ ei,
                        const float* __restrict__ bias, const float* __restrict__ g,
                        const float* __restrict__ b, float* __restrict__ h){
  __shared__ float red[128];
  __shared__ float den[NHEADS];
  int n = blockIdx.x, j = threadIdx.x;
  int p0 = off[n], p1 = off[n + 1];
  if (j < NHEADS){
    float s = 0.0f;
    for (int p = p0; p < p1; p++) s += ex[eid[p] * 4 + j];
    den[j] = s;
  }
  __syncthreads();
  int hh = j >> 5;
  float dinv = 1.0f / (den[hh] + 1e-16f);
  float agg = 0.0f;
  for (int p = p0; p < p1; p++){
    int e = eid[p];
    int s = ei[e];
    agg += ex[e * 4 + hh] * xl[s * HH + j];
  }
  agg *= dinv;
  float val = h[n * HH + j] + agg + bias[j];
  float mu = block_sum128(val, red) * (1.0f / HH);
  float d2 = val - mu;
  float var = block_sum128(d2 * d2, red) * (1.0f / HH);
  h[n * HH + j] = d2 * rsqrtf(var + 1e-5f) * g[j] + b[j];
}

// ---------------- global attention ----------------
__global__ void k_qkv(const float* __restrict__ h, const float* __restrict__ Win,
                      const float* __restrict__ bin, float* __restrict__ q,
                      float* __restrict__ kk, float* __restrict__ v){
  __shared__ float hs[HH];
  int n = blockIdx.x, j = threadIdx.x;
  hs[j] = h[n * HH + j];
  __syncthreads();
  float aq = bin[j], ak = bin[HH + j], av = bin[2 * HH + j];
  const float* wq = &Win[j * HH];
  const float* wk = &Win[(HH + j) * HH];
  const float* wv = &Win[(2 * HH + j) * HH];
  #pragma unroll 4
  for (int k = 0; k < HH; k++){ float hv = hs[k]; aq += hv * wq[k]; ak += hv * wk[k]; av += hv * wv[k]; }
  q[n * HH + j] = aq; kk[n * HH + j] = ak; v[n * HH + j] = av;
}

__global__ void k_attn_part(const float* __restrict__ q, const float* __restrict__ kk,
                            const float* __restrict__ v, float* __restrict__ pden,
                            float* __restrict__ pacc){
  __shared__ float ksh[64][36];
  __shared__ float vsh[64][36];
  int t = threadIdx.x;
  int qt = blockIdx.x, hh = blockIdx.y, ks = blockIdx.z;
  int qn = qt * 64 + t;
  float qreg[HDIM], acc[HDIM];
  #pragma unroll
  for (int d = 0; d < HDIM; d++){ qreg[d] = q[qn * HH + hh * HDIM + d]; acc[d] = 0.0f; }
  float den = 0.0f;
  const float scale = 0.17677669529663687f;
  for (int c = ks * (NN / KS); c < (ks + 1) * (NN / KS); c += 64){
    float tmpk[HDIM], tmpv[HDIM];
    #pragma unroll
    for (int d = 0; d < HDIM; d++){
      tmpk[d] = kk[(c + t) * HH + hh * HDIM + d];
      tmpv[d] = v [(c + t) * HH + hh * HDIM + d];
    }
    __syncthreads();
    #pragma unroll
    for (int d = 0; d < HDIM; d++){ ksh[t][d] = tmpk[d]; vsh[t][d] = tmpv[d]; }
    __syncthreads();
    for (int jj = 0; jj < 64; jj++){
      float s = 0.0f;
      #pragma unroll
      for (int d = 0; d < HDIM; d++) s += qreg[d] * ksh[jj][d];
      float e2 = expf(s * scale);
      den += e2;
      #pragma unroll
      for (int d = 0; d < HDIM; d++) acc[d] += e2 * vsh[jj][d];
    }
  }
  int pi = (qn * NHEADS + hh) * KS + ks;
  pden[pi] = den;
  #pragma unroll
  for (int d = 0; d < HDIM; d++) pacc[pi * HDIM + d] = acc[d];
}

__global__ void k_attn_out(const float* __restrict__ pden, const float* __restrict__ pacc,
                           const float* __restrict__ Wout, const float* __restrict__ bout,
                           const float* __restrict__ g, const float* __restrict__ b,
                           float* __restrict__ h){
  __shared__ float red[128];
  __shared__ float aos[HH];
  int n = blockIdx.x, j = threadIdx.x;
  int hh = j >> 5, d = j & 31;
  float ds = 0.0f, as = 0.0f;
  #pragma unroll
  for (int ks = 0; ks < KS; ks++){
    int pi = (n * NHEADS + hh) * KS + ks;
    ds += pden[pi];
    as += pacc[pi * HDIM + d];
  }
  aos[j] = as / ds;
  __syncthreads();
  float acc = bout[j];
  const float* w = &Wout[j * HH];
  #pragma unroll 4
  for (int k = 0; k < HH; k++) acc += aos[k] * w[k];
  float val = h[n * HH + j] + acc;
  float mu = block_sum128(val, red) * (1.0f / HH);
  float dd = val - mu;
  float var = block_sum128(dd * dd, red) * (1.0f / HH);
  h[n * HH + j] = dd * rsqrtf(var + 1e-5f) * g[j] + b[j];
}

// ---------------- bf16 prep for edge heads ----------------
// hb: h -> bf16 [NN*HH]; eab: edge_attr -> bf16 [EE*4];
// wb: [256][KPAD] bf16, rows 0-127 = mvW1, 128-255 = frW1, K zero-padded 260->KPAD
__global__ void k_prep(const float* __restrict__ h, const float* __restrict__ ea,
                       const float* __restrict__ mvW1, const float* __restrict__ frW1,
                       unsigned short* __restrict__ hb, unsigned short* __restrict__ eab,
                       unsigned short* __restrict__ wb){
  int idx = blockIdx.x * 256 + threadIdx.x;
  if (idx < NN * HH){
    hb[idx] = f2bf(h[idx]);
  } else if (idx < NN * HH + EE * 4){
    int i = idx - NN * HH;
    eab[i] = f2bf(ea[i]);
  } else {
    int i = idx - (NN * HH + EE * 4);
    if (i < 256 * KPAD){
      int n = i / KPAD, k = i - n * KPAD;
      float v = 0.0f;
      if (k < 2 * HH + EFEAT) v = (n < HH) ? mvW1[n * (2 * HH + EFEAT) + k]
                                           : frW1[(n - HH) * (2 * HH + EFEAT) + k];
      wb[i] = f2bf(v);
    }
  }
}

// ---------------- edge heads via MFMA ----------------
// Block: 64 edges, 256 threads (4 waves). Wave w owns edge rows [16w,16w+16).
// A (LDS): [64][KPAD] bf16 = h[src] ‖ h[dst] ‖ ea ‖ 0-pad. B (global): wb [256][KPAD].
// D[m][n] = 16x16x32 MFMA over 9 K-steps x 16 N-tiles; epilogue: +b1, gelu, dot W2,
// shfl-reduce across the 16 lanes of each quad, softplus, store.
__global__ __launch_bounds__(256) void k_edge_mfma(
    const unsigned short* __restrict__ hb, const unsigned short* __restrict__ eab,
    const int* __restrict__ ei, const unsigned short* __restrict__ wb,
    const float* __restrict__ mvb1, const float* __restrict__ frb1,
    const float* __restrict__ mvW2, const float* __restrict__ mvb2,
    const float* __restrict__ frW2, const float* __restrict__ frb2,
    float* __restrict__ out){
  __shared__ __align__(16) unsigned short As[64 * KPAD];
  int t = threadIdx.x;
  int e0 = blockIdx.x * 64;

  // ---- stage A: 4 threads per edge ----
  {
    int el = t >> 2, p = t & 3;
    int e = e0 + el;
    int node = (p < 2) ? ei[e] : ei[EE + e];
    int half = p & 1;
    const uint4* srcp = (const uint4*)(hb + node * HH + half * 64);
    uint4* dstp = (uint4*)(As + el * KPAD + (p >> 1) * 128 + half * 64);
    #pragma unroll
    for (int i = 0; i < 8; i++) dstp[i] = srcp[i];
    if (p == 0){
      unsigned short* tail = As + el * KPAD + 256;
      tail[0] = eab[e * 4];     tail[1] = eab[e * 4 + 1];
      tail[2] = eab[e * 4 + 2]; tail[3] = eab[e * 4 + 3];
      #pragma unroll
      for (int i = 4; i < KPAD - 256; i++) tail[i] = 0;
    }
  }

  int ln = t & 63, w = t >> 6;
  int lm = ln & 15, quad = ln >> 4;
  const unsigned short* abase = As + (16 * w + lm) * KPAD + quad * 8;
  const unsigned short* bbase = wb + lm * KPAD + quad * 8;

  f32x4 acc[16];
  #pragma unroll
  for (int i = 0; i < 16; i++) acc[i] = (f32x4){0.f, 0.f, 0.f, 0.f};

  __syncthreads();

  for (int ks = 0; ks < 9; ks++){
    union { uint4 u; bf16x8 v; } au;
    au.u = *(const uint4*)(abase + ks * 32);
    #pragma unroll
    for (int t2 = 0; t2 < 16; t2++){
      union { uint4 u; bf16x8 v; } bu;
      bu.u = *(const uint4*)(bbase + t2 * 16 * KPAD + ks * 32);
      acc[t2] = __builtin_amdgcn_mfma_f32_16x16x32_bf16(au.v, bu.v, acc[t2], 0, 0, 0);
    }
  }

  // ---- epilogue ----
  float sm[4] = {0.f, 0.f, 0.f, 0.f};
  float s0[4] = {0.f, 0.f, 0.f, 0.f};
  float s1[4] = {0.f, 0.f, 0.f, 0.f};
  #pragma unroll
  for (int t2 = 0; t2 < 16; t2++){
    int n = 16 * t2 + lm;
    float b1v, w2m, w20, w21;
    if (n < HH){ b1v = mvb1[n]; w2m = mvW2[n]; w20 = 0.f; w21 = 0.f; }
    else { int j = n - HH; b1v = frb1[j]; w2m = 0.f; w20 = frW2[j]; w21 = frW2[HH + j]; }
    #pragma unroll
    for (int r = 0; r < 4; r++){
      float g = gelu_f(acc[t2][r] + b1v);
      sm[r] += g * w2m; s0[r] += g * w20; s1[r] += g * w21;
    }
  }
  #pragma unroll
  for (int d = 1; d < 16; d <<= 1){
    #pragma unroll
    for (int r = 0; r < 4; r++){
      sm[r] += __shfl_xor(sm[r], d);
      s0[r] += __shfl_xor(s0[r], d);
      s1[r] += __shfl_xor(s1[r], d);
    }
  }
  if (lm == 0){
    #pragma unroll
    for (int r = 0; r < 4; r++){
      int e = e0 + 16 * w + 4 * quad + r;
      out[e]          = sm[r] + mvb2[0];
      out[EE + e]     = softplus_f(s0[r] + frb2[0]) + 1e-4f;
      out[2 * EE + e] = softplus_f(s1[r] + frb2[1]) + 1e-4f;
    }
  }
}

// ---------------- value head ----------------
__global__ void k_pool(const float* __restrict__ h, const unsigned char* __restrict__ mask,
                       float* __restrict__ gsum, float* __restrict__ msum, float* __restrict__ mcnt){
  int bb = blockIdx.x, j = threadIdx.x;
  float ga = 0.0f, ma = 0.0f;
  int n0 = bb * 32;
  for (int i = 0; i < 32; i++){
    int n = n0 + i;
    float v = h[n * HH + j];
    ga += v;
    if (mask[n]) ma += v;
  }
  atomicAdd(&gsum[j], ga);
  atomicAdd(&msum[j], ma);
  if (j == 0){
    float c = 0.0f;
    for (int i = 0; i < 32; i++) c += mask[n0 + i] ? 1.0f : 0.0f;
    atomicAdd(mcnt, c);
  }
}

__global__ void k_value(const float* __restrict__ gsum, const float* __restrict__ msum,
                        const float* __restrict__ mcnt,
                        const float* __restrict__ W1, const float* __restrict__ b1,
                        const float* __restrict__ W2, const float* __restrict__ b2,
                        float* __restrict__ out_val){
  __shared__ float red[128];
  __shared__ float vin[256];
  int j = threadIdx.x;
  float gp = gsum[j] * (1.0f / NN);
  float as = msum[j] * (1.0f / NN);
  float ac = fmaxf(mcnt[0] * (1.0f / NN), 1e-6f);
  vin[j] = gp; vin[HH + j] = as / ac;
  __syncthreads();
  float acc = b1[j];
  const float* w = &W1[j * 256];
  #pragma unroll 4
  for (int k = 0; k < 256; k++) acc += vin[k] * w[k];
  float hv = gelu_f(acc) * W2[j];
  float s = block_sum128(hv, red);
  if (j == 0) out_val[0] = s + b2[0];
}

extern "C" void kernel_launch(void* const* d_in, const int* in_sizes, int n_in,
                              void* d_out, int out_size, void* d_ws, size_t ws_size,
                              hipStream_t stream){
  (void)in_sizes; (void)n_in; (void)out_size; (void)ws_size;
  const float* x        = (const float*)d_in[0];
  const int*   ei       = (const int*)d_in[1];
  const float* ea       = (const float*)d_in[2];
  const float* u        = (const float*)d_in[3];
  const unsigned char* mask = (const unsigned char*)d_in[4];
  const float* tiles    = (const float*)d_in[5];
  const float* tf       = (const float*)d_in[7];
  const float* ne_W  = (const float*)d_in[8];
  const float* ne_b  = (const float*)d_in[9];
  const float* ne_g  = (const float*)d_in[10];
  const float* ne_be = (const float*)d_in[11];
  const float* ge_W  = (const float*)d_in[12];
  const float* ge_b  = (const float*)d_in[13];
  const float* ge_g  = (const float*)d_in[14];
  const float* ge_be = (const float*)d_in[15];
  const float* gru_Wih = (const float*)d_in[16];
  const float* gru_bih = (const float*)d_in[17];
  const float* gru_Whh = (const float*)d_in[18];
  const float* gru_bhh = (const float*)d_in[19];
  const float* gat_Wl  = (const float*)d_in[20];
  const float* gat_bl  = (const float*)d_in[21];
  const float* gat_Wr  = (const float*)d_in[22];
  const float* gat_br  = (const float*)d_in[23];
  const float* gat_We  = (const float*)d_in[24];
  const float* gat_att = (const float*)d_in[25];
  const float* gat_bias= (const float*)d_in[26];
  const float* ln_g    = (const float*)d_in[27];
  const float* ln_b    = (const float*)d_in[28];
  const float* attn_Win = (const float*)d_in[29];
  const float* attn_bin = (const float*)d_in[30];
  const float* attn_Wout= (const float*)d_in[31];
  const float* attn_bout= (const float*)d_in[32];
  const float* lng_g    = (const float*)d_in[33];
  const float* lng_b    = (const float*)d_in[34];
  const float* mv_W1 = (const float*)d_in[35];
  const float* mv_b1 = (const float*)d_in[36];
  const float* mv_W2 = (const float*)d_in[37];
  const float* mv_b2 = (const float*)d_in[38];
  const float* fr_W1 = (const float*)d_in[39];
  const float* fr_b1 = (const float*)d_in[40];
  const float* fr_W2 = (const float*)d_in[41];
  const float* fr_b2 = (const float*)d_in[42];
  const float* vl_W1 = (const float*)d_in[43];
  const float* vl_b1 = (const float*)d_in[44];
  const float* vl_W2 = (const float*)d_in[45];
  const float* vl_b2 = (const float*)d_in[46];

  // ---- workspace layout (float elements) ----
  float* ws   = (float*)d_ws;
  float* h    = ws;                  // 524288
  float* xl   = ws + 524288;         // 524288
  float* xr   = ws + 1048576;        // 524288
  float* ex   = ws + 1572864;        // 262144
  float* q    = ws + 1835008;        // 524288
  float* kbuf = ws + 2359296;        // 524288
  float* vbuf = ws + 2883584;        // 524288
  float* pden = ws + 3407872;        // 65536
  float* pacc = ws + 3473408;        // 2097152 (dead after k_attn_out -> reused for bf16 bufs)
  float* ue   = ws + 5570560;        // 128
  float* gsum = ws + 5570688;        // 128
  float* msum = gsum + 128;          // 128
  float* mcnt = gsum + 256;          // 1
  int*   cnt  = (int*)(ws + 5571072); // 4096
  int*   off  = cnt + NN;             // 4097
  int*   cur  = off + NN + 1;         // 4096
  int*   eid  = cur + NN;             // 65536

  // bf16 buffers aliased onto pacc (dead after k_attn_out; 16B-aligned offsets)
  unsigned short* hb  = (unsigned short*)pacc;                 // NN*HH = 524288 bf16
  unsigned short* eab = (unsigned short*)(pacc + 262144);      // EE*4  = 262144 bf16
  unsigned short* wb  = (unsigned short*)(pacc + 393216);      // 256*KPAD = 75776 bf16

  float* out       = (float*)d_out;
  float* out_val   = out + 3 * EE;
  float* out_tiles = out + 3 * EE + 1;

  // CSR of incoming edges
  hipMemsetAsync(cnt, 0, NN * sizeof(int), stream);
  k_hist   <<<EE / 256, 256, 0, stream>>>(ei, cnt);
  k_scan   <<<1, 256, 0, stream>>>(cnt, off, cur);
  k_scatter<<<EE / 256, 256, 0, stream>>>(ei, cur, eid);

  // encoders + GRU
  k_ue      <<<1, 128, 0, stream>>>(u, ge_W, ge_b, ge_g, ge_be, ue);
  k_node_enc<<<NN, 128, 0, stream>>>(x, tf, ne_W, ne_b, ne_g, ne_be, ue, h);
  k_gru     <<<NN, 128, 0, stream>>>(tiles, gru_Wih, gru_bih, gru_Whh, gru_bhh, h, out_tiles);

  // GATv2 stack
  for (int l = 0; l < NLAYERS; l++){
    k_xlxr <<<NN, 128, 0, stream>>>(h, gat_Wl + l * HH * HH, gat_bl + l * HH,
                                    gat_Wr + l * HH * HH, gat_br + l * HH, xl, xr);
    k_score<<<EE / 256, 256, 0, stream>>>(ei, ea, xl, xr,
                                          gat_We + l * HH * EFEAT,
                                          gat_att + l * NHEADS * HDIM, ex);
    k_aggln<<<NN, 128, 0, stream>>>(xl, ex, off, eid, ei,
                                    gat_bias + l * HH, ln_g + l * HH, ln_b + l * HH, h);
  }

  // global attention
  k_qkv<<<NN, 128, 0, stream>>>(h, attn_Win, attn_bin, q, kbuf, vbuf);
  dim3 gattn(NN / 64, NHEADS, KS);
  k_attn_part<<<gattn, 64, 0, stream>>>(q, kbuf, vbuf, pden, pacc);
  k_attn_out <<<NN, 128, 0, stream>>>(pden, pacc, attn_Wout, attn_bout, lng_g, lng_b, h);

  // edge heads (bf16 MFMA)
  {
    int total = NN * HH + EE * 4 + 256 * KPAD;
    k_prep<<<(total + 255) / 256, 256, 0, stream>>>(h, ea, mv_W1, fr_W1, hb, eab, wb);
    k_edge_mfma<<<EE / 64, 256, 0, stream>>>(hb, eab, ei, wb, mv_b1, fr_b1,
                                             mv_W2, mv_b2, fr_W2, fr_b2, out);
  }

  // value head
  hipMemsetAsync(gsum, 0, 257 * sizeof(float), stream);
  k_pool <<<128, 128, 0, stream>>>(h, mask, gsum, msum, mcnt);
  k_value<<<1, 128, 0, stream>>>(gsum, msum, mcnt, vl_W1, vl_b1, vl_W2, vl_b2, out_val);
}

// Round 3
// 1356.775 us; speedup vs baseline: 1.7611x; 1.2111x over previous
//
#include <hip/hip_runtime.h>
#include <math.h>

// StrategistGNN forward on MI355X. Round 3: MFMA flash attention for the global
// self-attention (+ round-2 bf16 MFMA edge heads).
// N=4096 nodes, E=65536 edges, H=128, 4 heads x 32, L=4 GAT layers, B=1.

#define NN 4096
#define EE 65536
#define HH 128
#define NHEADS 4
#define HDIM 32
#define NLAYERS 4
#define NFEAT 16
#define GFEAT 8
#define EFEAT 4
#define KS 4     // key-splits for global attention
#define KPAD 296 // padded K stride (bf16 elems) for edge-head GEMM
#define PSTR 40  // P-tile LDS row stride (bf16): 16B-aligned b128 reads, <=2-way write conflicts

typedef short bf16x8 __attribute__((ext_vector_type(8)));
typedef float f32x4  __attribute__((ext_vector_type(4)));

__device__ __forceinline__ float gelu_f(float x){
  return 0.5f * x * (1.0f + erff(x * 0.7071067811865475f));
}
__device__ __forceinline__ float sigm(float x){ return 1.0f / (1.0f + expf(-x)); }
__device__ __forceinline__ float softplus_f(float x){ return x > 20.0f ? x : log1pf(expf(x)); }
__device__ __forceinline__ unsigned short f2bf(float x){
  unsigned u = __float_as_uint(x);
  unsigned r = (u + 0x7FFFu + ((u >> 16) & 1u)) >> 16;
  return (unsigned short)r;
}

__device__ __forceinline__ float block_sum128(float v, float* red){
  int j = threadIdx.x;
  red[j] = v; __syncthreads();
  for (int s = 64; s > 0; s >>= 1){
    if (j < s) red[j] += red[j + s];
    __syncthreads();
  }
  float r = red[0];
  __syncthreads();
  return r;
}

// ---------------- CSR build (incoming edges per dst) ----------------
__global__ void k_hist(const int* __restrict__ ei, int* __restrict__ cnt){
  int e = blockIdx.x * 256 + threadIdx.x;
  if (e < EE) atomicAdd(&cnt[ei[EE + e]], 1);
}

__global__ void k_scan(const int* __restrict__ cnt, int* __restrict__ off, int* __restrict__ cur){
  __shared__ int part[256];
  int t = threadIdx.x;
  int local[16];
  int s = 0;
  #pragma unroll
  for (int i = 0; i < 16; i++){ local[i] = s; s += cnt[t * 16 + i]; }
  part[t] = s; __syncthreads();
  for (int o = 1; o < 256; o <<= 1){
    int v = (t >= o) ? part[t - o] : 0;
    __syncthreads();
    part[t] += v;
    __syncthreads();
  }
  int base = part[t] - s;
  #pragma unroll
  for (int i = 0; i < 16; i++){ int o = base + local[i]; off[t * 16 + i] = o; cur[t * 16 + i] = o; }
  if (t == 255) off[NN] = part[255];
}

__global__ void k_scatter(const int* __restrict__ ei, int* __restrict__ cur, int* __restrict__ eid){
  int e = blockIdx.x * 256 + threadIdx.x;
  if (e < EE){
    int d = ei[EE + e];
    int p = atomicAdd(&cur[d], 1);
    eid[p] = e;
  }
}

// ---------------- encoders ----------------
__global__ void k_ue(const float* __restrict__ u, const float* __restrict__ W,
                     const float* __restrict__ b, const float* __restrict__ g,
                     const float* __restrict__ be, float* __restrict__ ue){
  __shared__ float red[128];
  __shared__ float us[GFEAT];
  int j = threadIdx.x;
  if (j < GFEAT) us[j] = u[j];
  __syncthreads();
  float acc = b[j];
  #pragma unroll
  for (int k = 0; k < GFEAT; k++) acc += us[k] * W[j * GFEAT + k];
  float mu = block_sum128(acc, red) * (1.0f / HH);
  float d = acc - mu;
  float var = block_sum128(d * d, red) * (1.0f / HH);
  ue[j] = gelu_f(d * rsqrtf(var + 1e-5f) * g[j] + be[j]);
}

__global__ void k_node_enc(const float* __restrict__ x, const float* __restrict__ tf,
                           const float* __restrict__ W, const float* __restrict__ b,
                           const float* __restrict__ g, const float* __restrict__ be,
                           const float* __restrict__ ue, float* __restrict__ h){
  __shared__ float red[128];
  __shared__ float xs[NFEAT + 1];
  int n = blockIdx.x, j = threadIdx.x;
  if (j < NFEAT) xs[j] = x[n * NFEAT + j];
  if (j == NFEAT) xs[NFEAT] = tf[0];
  __syncthreads();
  float acc = b[j];
  #pragma unroll
  for (int k = 0; k < NFEAT + 1; k++) acc += xs[k] * W[j * (NFEAT + 1) + k];
  float mu = block_sum128(acc, red) * (1.0f / HH);
  float d = acc - mu;
  float var = block_sum128(d * d, red) * (1.0f / HH);
  h[n * HH + j] = gelu_f(d * rsqrtf(var + 1e-5f) * g[j] + be[j]) + ue[j];
}

// ---------------- GRU ----------------
__global__ void k_gru(const float* __restrict__ tiles, const float* __restrict__ Wih,
                      const float* __restrict__ bih, const float* __restrict__ Whh,
                      const float* __restrict__ bhh, float* __restrict__ h,
                      float* __restrict__ out_tiles){
  __shared__ float hs[HH], ts[HH];
  int n = blockIdx.x, j = threadIdx.x;
  hs[j] = h[n * HH + j]; ts[j] = tiles[n * HH + j];
  __syncthreads();
  float ir = bih[j], iz = bih[HH + j], in_ = bih[2 * HH + j];
  float hr = bhh[j], hz = bhh[HH + j], hn = bhh[2 * HH + j];
  const float* wr = &Wih[j * HH];            const float* vr = &Whh[j * HH];
  const float* wz = &Wih[(HH + j) * HH];     const float* vz = &Whh[(HH + j) * HH];
  const float* wn = &Wih[(2 * HH + j) * HH]; const float* vn = &Whh[(2 * HH + j) * HH];
  #pragma unroll 4
  for (int k = 0; k < HH; k++){
    float hv = hs[k], tv = ts[k];
    ir += hv * wr[k]; iz += hv * wz[k]; in_ += hv * wn[k];
    hr += tv * vr[k]; hz += tv * vz[k]; hn += tv * vn[k];
  }
  float r = sigm(ir + hr), z = sigm(iz + hz);
  float nn2 = tanhf(in_ + r * hn);
  float hnew = (1.0f - z) * nn2 + z * ts[j];
  h[n * HH + j] = hnew;
  out_tiles[n * HH + j] = hnew;
}

// ---------------- GATv2 layer pieces ----------------
__global__ void k_xlxr(const float* __restrict__ h, const float* __restrict__ Wl,
                       const float* __restrict__ bl, const float* __restrict__ Wr,
                       const float* __restrict__ br, float* __restrict__ xl, float* __restrict__ xr){
  __shared__ float hs[HH];
  int n = blockIdx.x, j = threadIdx.x;
  hs[j] = h[n * HH + j];
  __syncthreads();
  float al = bl[j], ar = br[j];
  const float* wl = &Wl[j * HH]; const float* wr = &Wr[j * HH];
  #pragma unroll 4
  for (int k = 0; k < HH; k++){ float hv = hs[k]; al += hv * wl[k]; ar += hv * wr[k]; }
  xl[n * HH + j] = al; xr[n * HH + j] = ar;
}

__global__ void k_score(const int* __restrict__ ei, const float* __restrict__ ea,
                        const float* __restrict__ xl, const float* __restrict__ xr,
                        const float* __restrict__ We, const float* __restrict__ att,
                        float* __restrict__ ex){
  int e = blockIdx.x * 256 + threadIdx.x;
  if (e >= EE) return;
  int s = ei[e], d = ei[EE + e];
  float a0 = ea[e * 4], a1 = ea[e * 4 + 1], a2 = ea[e * 4 + 2], a3 = ea[e * 4 + 3];
  const float* xls = &xl[s * HH];
  const float* xrd = &xr[d * HH];
  #pragma unroll
  for (int hh = 0; hh < NHEADS; hh++){
    float sc = 0.0f;
    #pragma unroll
    for (int dd = 0; dd < HDIM; dd++){
      int j = hh * HDIM + dd;
      float eev = a0 * We[j * 4] + a1 * We[j * 4 + 1] + a2 * We[j * 4 + 2] + a3 * We[j * 4 + 3];
      float v = xls[j] + xrd[j] + eev;
      v = v > 0.0f ? v : 0.2f * v;
      sc += v * att[j];
    }
    ex[e * 4 + hh] = expf(sc);
  }
}

__global__ void k_aggln(const float* __restrict__ xl, const float* __restrict__ ex,
                        const int* __restrict__ off, const int* __restrict__ eid,
                        const int* __restrict__ ei,
                        const float* __restrict__ bias, const float* __restrict__ g,
                        const float* __restrict__ b, float* __restrict__ h){
  __shared__ float red[128];
  __shared__ float den[NHEADS];
  int n = blockIdx.x, j = threadIdx.x;
  int p0 = off[n], p1 = off[n + 1];
  if (j < NHEADS){
    float s = 0.0f;
    for (int p = p0; p < p1; p++) s += ex[eid[p] * 4 + j];
    den[j] = s;
  }
  __syncthreads();
  int hh = j >> 5;
  float dinv = 1.0f / (den[hh] + 1e-16f);
  float agg = 0.0f;
  for (int p = p0; p < p1; p++){
    int e = eid[p];
    int s = ei[e];
    agg += ex[e * 4 + hh] * xl[s * HH + j];
  }
  agg *= dinv;
  float val = h[n * HH + j] + agg + bias[j];
  float mu = block_sum128(val, red) * (1.0f / HH);
  float d2 = val - mu;
  float var = block_sum128(d2 * d2, red) * (1.0f / HH);
  h[n * HH + j] = d2 * rsqrtf(var + 1e-5f) * g[j] + b[j];
}

// ---------------- global attention ----------------
// qb,kb: bf16 [NN][HH]; vt: bf16 [NHEADS*HDIM][NN] (transposed V)
__global__ void k_qkv(const float* __restrict__ h, const float* __restrict__ Win,
                      const float* __restrict__ bin, unsigned short* __restrict__ qb,
                      unsigned short* __restrict__ kb, unsigned short* __restrict__ vt){
  __shared__ float hs[HH];
  int n = blockIdx.x, j = threadIdx.x;
  hs[j] = h[n * HH + j];
  __syncthreads();
  float aq = bin[j], ak = bin[HH + j], av = bin[2 * HH + j];
  const float* wq = &Win[j * HH];
  const float* wk = &Win[(HH + j) * HH];
  const float* wv = &Win[(2 * HH + j) * HH];
  #pragma unroll 4
  for (int k = 0; k < HH; k++){ float hv = hs[k]; aq += hv * wq[k]; ak += hv * wk[k]; av += hv * wv[k]; }
  qb[n * HH + j] = f2bf(aq);
  kb[n * HH + j] = f2bf(ak);
  vt[j * NN + n] = f2bf(av);
}

// MFMA flash attention (partial over a key-split).
// Grid (NN/64, NHEADS, KS); 256 threads = 4 waves; wave w: queries [64*bx+16w, +16).
// Per 32-key chunk: St[key][q] = K-tile x Q^T via 2x mfma_16x16x32 (A=K rows, B=Q rows);
// exp -> bf16 -> LDS P[q][key] (stride PSTR); P as A-frag, vt rows as B-frag -> 2x mfma
// accumulate O[q][d]. den via per-lane sum + shfl_xor over quads. Writes pden/pacc
// in the same format as the old splitter so k_attn_out is unchanged.
__global__ __launch_bounds__(256) void k_attn_flash(
    const unsigned short* __restrict__ qb, const unsigned short* __restrict__ kb,
    const unsigned short* __restrict__ vt,
    float* __restrict__ pden, float* __restrict__ pacc){
  __shared__ __align__(16) unsigned short Pl[4][16 * PSTR];
  int t = threadIdx.x, w = t >> 6, ln = t & 63;
  int c = ln & 15, qd = ln >> 4;
  int hh = blockIdx.y, ks = blockIdx.z;
  int q0 = blockIdx.x * 64 + w * 16;
  union { uint4 u; bf16x8 v; } qf;
  qf.u = *(const uint4*)(qb + (q0 + c) * HH + hh * HDIM + qd * 8);
  f32x4 o0 = {0.f,0.f,0.f,0.f}, o1 = {0.f,0.f,0.f,0.f};
  float denp = 0.f;
  const float scale = 0.17677669529663687f;  // 1/sqrt(32)
  unsigned short* P = &Pl[w][0];
  const unsigned short* vrow0 = vt + (hh * HDIM + c) * NN;
  const unsigned short* vrow1 = vt + (hh * HDIM + 16 + c) * NN;
  for (int k0 = ks * (NN / KS); k0 < (ks + 1) * (NN / KS); k0 += 32){
    #pragma unroll
    for (int tt = 0; tt < 2; tt++){
      union { uint4 u; bf16x8 v; } kf;
      kf.u = *(const uint4*)(kb + (k0 + tt * 16 + c) * HH + hh * HDIM + qd * 8);
      f32x4 s = {0.f,0.f,0.f,0.f};
      s = __builtin_amdgcn_mfma_f32_16x16x32_bf16(kf.v, qf.v, s, 0, 0, 0);
      // lane holds St[key = tt*16 + qd*4 + r][q = c]
      float e0 = expf(s[0] * scale), e1 = expf(s[1] * scale);
      float e2 = expf(s[2] * scale), e3 = expf(s[3] * scale);
      denp += (e0 + e1) + (e2 + e3);
      unsigned p01 = (unsigned)f2bf(e0) | ((unsigned)f2bf(e1) << 16);
      unsigned p23 = (unsigned)f2bf(e2) | ((unsigned)f2bf(e3) << 16);
      *(unsigned*)(P + c * PSTR + tt * 16 + qd * 4)     = p01;
      *(unsigned*)(P + c * PSTR + tt * 16 + qd * 4 + 2) = p23;
    }
    union { uint4 u; bf16x8 v; } af, b0, b1;
    af.u = *(const uint4*)(P + c * PSTR + qd * 8);
    b0.u = *(const uint4*)(vrow0 + k0 + qd * 8);
    b1.u = *(const uint4*)(vrow1 + k0 + qd * 8);
    o0 = __builtin_amdgcn_mfma_f32_16x16x32_bf16(af.v, b0.v, o0, 0, 0, 0);
    o1 = __builtin_amdgcn_mfma_f32_16x16x32_bf16(af.v, b1.v, o1, 0, 0, 0);
  }
  denp += __shfl_xor(denp, 16);
  denp += __shfl_xor(denp, 32);     // all lanes: den for q = q0 + c
  if (qd == 0) pden[((q0 + c) * NHEADS + hh) * KS + ks] = denp;
  #pragma unroll
  for (int r = 0; r < 4; r++){
    int qn = q0 + qd * 4 + r;
    int pi = (qn * NHEADS + hh) * KS + ks;
    pacc[pi * HDIM + c]      = o0[r];
    pacc[pi * HDIM + 16 + c] = o1[r];
  }
}

__global__ void k_attn_out(const float* __restrict__ pden, const float* __restrict__ pacc,
                           const float* __restrict__ Wout, const float* __restrict__ bout,
                           const float* __restrict__ g, const float* __restrict__ b,
                           float* __restrict__ h){
  __shared__ float red[128];
  __shared__ float aos[HH];
  int n = blockIdx.x, j = threadIdx.x;
  int hh = j >> 5, d = j & 31;
  float ds = 0.0f, as = 0.0f;
  #pragma unroll
  for (int ks = 0; ks < KS; ks++){
    int pi = (n * NHEADS + hh) * KS + ks;
    ds += pden[pi];
    as += pacc[pi * HDIM + d];
  }
  aos[j] = as / ds;
  __syncthreads();
  float acc = bout[j];
  const float* w = &Wout[j * HH];
  #pragma unroll 4
  for (int k = 0; k < HH; k++) acc += aos[k] * w[k];
  float val = h[n * HH + j] + acc;
  float mu = block_sum128(val, red) * (1.0f / HH);
  float dd = val - mu;
  float var = block_sum128(dd * dd, red) * (1.0f / HH);
  h[n * HH + j] = dd * rsqrtf(var + 1e-5f) * g[j] + b[j];
}

// ---------------- bf16 prep for edge heads ----------------
__global__ void k_prep(const float* __restrict__ h, const float* __restrict__ ea,
                       const float* __restrict__ mvW1, const float* __restrict__ frW1,
                       unsigned short* __restrict__ hb, unsigned short* __restrict__ eab,
                       unsigned short* __restrict__ wb){
  int idx = blockIdx.x * 256 + threadIdx.x;
  if (idx < NN * HH){
    hb[idx] = f2bf(h[idx]);
  } else if (idx < NN * HH + EE * 4){
    int i = idx - NN * HH;
    eab[i] = f2bf(ea[i]);
  } else {
    int i = idx - (NN * HH + EE * 4);
    if (i < 256 * KPAD){
      int n = i / KPAD, k = i - n * KPAD;
      float v = 0.0f;
      if (k < 2 * HH + EFEAT) v = (n < HH) ? mvW1[n * (2 * HH + EFEAT) + k]
                                           : frW1[(n - HH) * (2 * HH + EFEAT) + k];
      wb[i] = f2bf(v);
    }
  }
}

// ---------------- edge heads via MFMA ----------------
__global__ __launch_bounds__(256) void k_edge_mfma(
    const unsigned short* __restrict__ hb, const unsigned short* __restrict__ eab,
    const int* __restrict__ ei, const unsigned short* __restrict__ wb,
    const float* __restrict__ mvb1, const float* __restrict__ frb1,
    const float* __restrict__ mvW2, const float* __restrict__ mvb2,
    const float* __restrict__ frW2, const float* __restrict__ frb2,
    float* __restrict__ out){
  __shared__ __align__(16) unsigned short As[64 * KPAD];
  int t = threadIdx.x;
  int e0 = blockIdx.x * 64;
  {
    int el = t >> 2, p = t & 3;
    int e = e0 + el;
    int node = (p < 2) ? ei[e] : ei[EE + e];
    int half = p & 1;
    const uint4* srcp = (const uint4*)(hb + node * HH + half * 64);
    uint4* dstp = (uint4*)(As + el * KPAD + (p >> 1) * 128 + half * 64);
    #pragma unroll
    for (int i = 0; i < 8; i++) dstp[i] = srcp[i];
    if (p == 0){
      unsigned short* tail = As + el * KPAD + 256;
      tail[0] = eab[e * 4];     tail[1] = eab[e * 4 + 1];
      tail[2] = eab[e * 4 + 2]; tail[3] = eab[e * 4 + 3];
      #pragma unroll
      for (int i = 4; i < KPAD - 256; i++) tail[i] = 0;
    }
  }
  int ln = t & 63, w = t >> 6;
  int lm = ln & 15, quad = ln >> 4;
  const unsigned short* abase = As + (16 * w + lm) * KPAD + quad * 8;
  const unsigned short* bbase = wb + lm * KPAD + quad * 8;
  f32x4 acc[16];
  #pragma unroll
  for (int i = 0; i < 16; i++) acc[i] = (f32x4){0.f, 0.f, 0.f, 0.f};
  __syncthreads();
  for (int ks = 0; ks < 9; ks++){
    union { uint4 u; bf16x8 v; } au;
    au.u = *(const uint4*)(abase + ks * 32);
    #pragma unroll
    for (int t2 = 0; t2 < 16; t2++){
      union { uint4 u; bf16x8 v; } bu;
      bu.u = *(const uint4*)(bbase + t2 * 16 * KPAD + ks * 32);
      acc[t2] = __builtin_amdgcn_mfma_f32_16x16x32_bf16(au.v, bu.v, acc[t2], 0, 0, 0);
    }
  }
  float sm[4] = {0.f, 0.f, 0.f, 0.f};
  float s0[4] = {0.f, 0.f, 0.f, 0.f};
  float s1[4] = {0.f, 0.f, 0.f, 0.f};
  #pragma unroll
  for (int t2 = 0; t2 < 16; t2++){
    int n = 16 * t2 + lm;
    float b1v, w2m, w20, w21;
    if (n < HH){ b1v = mvb1[n]; w2m = mvW2[n]; w20 = 0.f; w21 = 0.f; }
    else { int j = n - HH; b1v = frb1[j]; w2m = 0.f; w20 = frW2[j]; w21 = frW2[HH + j]; }
    #pragma unroll
    for (int r = 0; r < 4; r++){
      float g = gelu_f(acc[t2][r] + b1v);
      sm[r] += g * w2m; s0[r] += g * w20; s1[r] += g * w21;
    }
  }
  #pragma unroll
  for (int d = 1; d < 16; d <<= 1){
    #pragma unroll
    for (int r = 0; r < 4; r++){
      sm[r] += __shfl_xor(sm[r], d);
      s0[r] += __shfl_xor(s0[r], d);
      s1[r] += __shfl_xor(s1[r], d);
    }
  }
  if (lm == 0){
    #pragma unroll
    for (int r = 0; r < 4; r++){
      int e = e0 + 16 * w + 4 * quad + r;
      out[e]          = sm[r] + mvb2[0];
      out[EE + e]     = softplus_f(s0[r] + frb2[0]) + 1e-4f;
      out[2 * EE + e] = softplus_f(s1[r] + frb2[1]) + 1e-4f;
    }
  }
}

// ---------------- value head ----------------
__global__ void k_pool(const float* __restrict__ h, const unsigned char* __restrict__ mask,
                       float* __restrict__ gsum, float* __restrict__ msum, float* __restrict__ mcnt){
  int bb = blockIdx.x, j = threadIdx.x;
  float ga = 0.0f, ma = 0.0f;
  int n0 = bb * 32;
  for (int i = 0; i < 32; i++){
    int n = n0 + i;
    float v = h[n * HH + j];
    ga += v;
    if (mask[n]) ma += v;
  }
  atomicAdd(&gsum[j], ga);
  atomicAdd(&msum[j], ma);
  if (j == 0){
    float c = 0.0f;
    for (int i = 0; i < 32; i++) c += mask[n0 + i] ? 1.0f : 0.0f;
    atomicAdd(mcnt, c);
  }
}

__global__ void k_value(const float* __restrict__ gsum, const float* __restrict__ msum,
                        const float* __restrict__ mcnt,
                        const float* __restrict__ W1, const float* __restrict__ b1,
                        const float* __restrict__ W2, const float* __restrict__ b2,
                        float* __restrict__ out_val){
  __shared__ float red[128];
  __shared__ float vin[256];
  int j = threadIdx.x;
  float gp = gsum[j] * (1.0f / NN);
  float as = msum[j] * (1.0f / NN);
  float ac = fmaxf(mcnt[0] * (1.0f / NN), 1e-6f);
  vin[j] = gp; vin[HH + j] = as / ac;
  __syncthreads();
  float acc = b1[j];
  const float* w = &W1[j * 256];
  #pragma unroll 4
  for (int k = 0; k < 256; k++) acc += vin[k] * w[k];
  float hv = gelu_f(acc) * W2[j];
  float s = block_sum128(hv, red);
  if (j == 0) out_val[0] = s + b2[0];
}

extern "C" void kernel_launch(void* const* d_in, const int* in_sizes, int n_in,
                              void* d_out, int out_size, void* d_ws, size_t ws_size,
                              hipStream_t stream){
  (void)in_sizes; (void)n_in; (void)out_size; (void)ws_size;
  const float* x        = (const float*)d_in[0];
  const int*   ei       = (const int*)d_in[1];
  const float* ea       = (const float*)d_in[2];
  const float* u        = (const float*)d_in[3];
  const unsigned char* mask = (const unsigned char*)d_in[4];
  const float* tiles    = (const float*)d_in[5];
  const float* tf       = (const float*)d_in[7];
  const float* ne_W  = (const float*)d_in[8];
  const float* ne_b  = (const float*)d_in[9];
  const float* ne_g  = (const float*)d_in[10];
  const float* ne_be = (const float*)d_in[11];
  const float* ge_W  = (const float*)d_in[12];
  const float* ge_b  = (const float*)d_in[13];
  const float* ge_g  = (const float*)d_in[14];
  const float* ge_be = (const float*)d_in[15];
  const float* gru_Wih = (const float*)d_in[16];
  const float* gru_bih = (const float*)d_in[17];
  const float* gru_Whh = (const float*)d_in[18];
  const float* gru_bhh = (const float*)d_in[19];
  const float* gat_Wl  = (const float*)d_in[20];
  const float* gat_bl  = (const float*)d_in[21];
  const float* gat_Wr  = (const float*)d_in[22];
  const float* gat_br  = (const float*)d_in[23];
  const float* gat_We  = (const float*)d_in[24];
  const float* gat_att = (const float*)d_in[25];
  const float* gat_bias= (const float*)d_in[26];
  const float* ln_g    = (const float*)d_in[27];
  const float* ln_b    = (const float*)d_in[28];
  const float* attn_Win = (const float*)d_in[29];
  const float* attn_bin = (const float*)d_in[30];
  const float* attn_Wout= (const float*)d_in[31];
  const float* attn_bout= (const float*)d_in[32];
  const float* lng_g    = (const float*)d_in[33];
  const float* lng_b    = (const float*)d_in[34];
  const float* mv_W1 = (const float*)d_in[35];
  const float* mv_b1 = (const float*)d_in[36];
  const float* mv_W2 = (const float*)d_in[37];
  const float* mv_b2 = (const float*)d_in[38];
  const float* fr_W1 = (const float*)d_in[39];
  const float* fr_b1 = (const float*)d_in[40];
  const float* fr_W2 = (const float*)d_in[41];
  const float* fr_b2 = (const float*)d_in[42];
  const float* vl_W1 = (const float*)d_in[43];
  const float* vl_b1 = (const float*)d_in[44];
  const float* vl_W2 = (const float*)d_in[45];
  const float* vl_b2 = (const float*)d_in[46];

  // ---- workspace layout (float elements) ----
  float* ws   = (float*)d_ws;
  float* h    = ws;                  // 524288
  float* xl   = ws + 524288;         // 524288
  float* xr   = ws + 1048576;        // 524288
  float* ex   = ws + 1572864;        // 262144
  float* qkvb = ws + 1835008;        // 3*262144 f32 = qb/kb/vt bf16 buffers
  float* pden = ws + 3407872;        // 65536
  float* pacc = ws + 3473408;        // 2097152 (dead after k_attn_out -> bf16 edge bufs)
  float* ue   = ws + 5570560;        // 128
  float* gsum = ws + 5570688;        // 128
  float* msum = gsum + 128;
  float* mcnt = gsum + 256;
  int*   cnt  = (int*)(ws + 5571072); // 4096
  int*   off  = cnt + NN;             // 4097
  int*   cur  = off + NN + 1;         // 4096
  int*   eid  = cur + NN;             // 65536

  unsigned short* qb = (unsigned short*)qkvb;                // NN*HH bf16
  unsigned short* kb = (unsigned short*)(qkvb + 262144);     // NN*HH bf16
  unsigned short* vt = (unsigned short*)(qkvb + 524288);     // NHEADS*HDIM*NN bf16

  unsigned short* hb  = (unsigned short*)pacc;               // NN*HH bf16
  unsigned short* eab = (unsigned short*)(pacc + 262144);    // EE*4 bf16
  unsigned short* wb  = (unsigned short*)(pacc + 393216);    // 256*KPAD bf16

  float* out       = (float*)d_out;
  float* out_val   = out + 3 * EE;
  float* out_tiles = out + 3 * EE + 1;

  // CSR of incoming edges
  hipMemsetAsync(cnt, 0, NN * sizeof(int), stream);
  k_hist   <<<EE / 256, 256, 0, stream>>>(ei, cnt);
  k_scan   <<<1, 256, 0, stream>>>(cnt, off, cur);
  k_scatter<<<EE / 256, 256, 0, stream>>>(ei, cur, eid);

  // encoders + GRU
  k_ue      <<<1, 128, 0, stream>>>(u, ge_W, ge_b, ge_g, ge_be, ue);
  k_node_enc<<<NN, 128, 0, stream>>>(x, tf, ne_W, ne_b, ne_g, ne_be, ue, h);
  k_gru     <<<NN, 128, 0, stream>>>(tiles, gru_Wih, gru_bih, gru_Whh, gru_bhh, h, out_tiles);

  // GATv2 stack
  for (int l = 0; l < NLAYERS; l++){
    k_xlxr <<<NN, 128, 0, stream>>>(h, gat_Wl + l * HH * HH, gat_bl + l * HH,
                                    gat_Wr + l * HH * HH, gat_br + l * HH, xl, xr);
    k_score<<<EE / 256, 256, 0, stream>>>(ei, ea, xl, xr,
                                          gat_We + l * HH * EFEAT,
                                          gat_att + l * NHEADS * HDIM, ex);
    k_aggln<<<NN, 128, 0, stream>>>(xl, ex, off, eid, ei,
                                    gat_bias + l * HH, ln_g + l * HH, ln_b + l * HH, h);
  }

  // global attention (MFMA flash, key-split partials + combine)
  k_qkv<<<NN, 128, 0, stream>>>(h, attn_Win, attn_bin, qb, kb, vt);
  dim3 gattn(NN / 64, NHEADS, KS);
  k_attn_flash<<<gattn, 256, 0, stream>>>(qb, kb, vt, pden, pacc);
  k_attn_out <<<NN, 128, 0, stream>>>(pden, pacc, attn_Wout, attn_bout, lng_g, lng_b, h);

  // edge heads (bf16 MFMA)
  {
    int total = NN * HH + EE * 4 + 256 * KPAD;
    k_prep<<<(total + 255) / 256, 256, 0, stream>>>(h, ea, mv_W1, fr_W1, hb, eab, wb);
    k_edge_mfma<<<EE / 64, 256, 0, stream>>>(hb, eab, ei, wb, mv_b1, fr_b1,
                                             mv_W2, mv_b2, fr_W2, fr_b2, out);
  }

  // value head
  hipMemsetAsync(gsum, 0, 257 * sizeof(float), stream);
  k_pool <<<128, 128, 0, stream>>>(h, mask, gsum, msum, mcnt);
  k_value<<<1, 128, 0, stream>>>(gsum, msum, mcnt, vl_W1, vl_b1, vl_W2, vl_b2, out_val);
}

// Round 4
// 642.330 us; speedup vs baseline: 3.7200x; 2.1123x over previous
//
#include <hip/hip_runtime.h>
#include <math.h>

// StrategistGNN forward on MI355X. Round 4: all N x 128 dense projections via
// generic bf16 MFMA GEMM (k_lin); GRU/xlxr/qkv/attn-out scalar kernels removed.
// N=4096 nodes, E=65536 edges, H=128, 4 heads x 32, L=4 GAT layers, B=1.

#define NN 4096
#define EE 65536
#define HH 128
#define NHEADS 4
#define HDIM 32
#define NLAYERS 4
#define NFEAT 16
#define GFEAT 8
#define EFEAT 4
#define KS 2     // key-splits for global attention
#define KPAD 296 // padded K stride (bf16) for edge-head GEMM
#define XSTR 136 // k_lin LDS row stride (bf16): 2-way bank aliasing only (free)

typedef short bf16x8 __attribute__((ext_vector_type(8)));
typedef float f32x4  __attribute__((ext_vector_type(4)));

__device__ __forceinline__ float gelu_f(float x){
  return 0.5f * x * (1.0f + erff(x * 0.7071067811865475f));
}
__device__ __forceinline__ float sigm(float x){ return 1.0f / (1.0f + expf(-x)); }
__device__ __forceinline__ float softplus_f(float x){ return x > 20.0f ? x : log1pf(expf(x)); }
__device__ __forceinline__ unsigned short f2bf(float x){
  unsigned u = __float_as_uint(x);
  unsigned r = (u + 0x7FFFu + ((u >> 16) & 1u)) >> 16;
  return (unsigned short)r;
}

__device__ __forceinline__ float block_sum128(float v, float* red){
  int j = threadIdx.x;
  red[j] = v; __syncthreads();
  for (int s = 64; s > 0; s >>= 1){
    if (j < s) red[j] += red[j + s];
    __syncthreads();
  }
  float r = red[0];
  __syncthreads();
  return r;
}

// ---------------- CSR build ----------------
__global__ void k_hist(const int* __restrict__ ei, int* __restrict__ cnt){
  int e = blockIdx.x * 256 + threadIdx.x;
  if (e < EE) atomicAdd(&cnt[ei[EE + e]], 1);
}

__global__ void k_scan(const int* __restrict__ cnt, int* __restrict__ off, int* __restrict__ cur){
  __shared__ int part[256];
  int t = threadIdx.x;
  int local[16];
  int s = 0;
  #pragma unroll
  for (int i = 0; i < 16; i++){ local[i] = s; s += cnt[t * 16 + i]; }
  part[t] = s; __syncthreads();
  for (int o = 1; o < 256; o <<= 1){
    int v = (t >= o) ? part[t - o] : 0;
    __syncthreads();
    part[t] += v;
    __syncthreads();
  }
  int base = part[t] - s;
  #pragma unroll
  for (int i = 0; i < 16; i++){ int o = base + local[i]; off[t * 16 + i] = o; cur[t * 16 + i] = o; }
  if (t == 255) off[NN] = part[255];
}

__global__ void k_scatter(const int* __restrict__ ei, int* __restrict__ cur, int* __restrict__ eid){
  int e = blockIdx.x * 256 + threadIdx.x;
  if (e < EE){
    int d = ei[EE + e];
    int p = atomicAdd(&cur[d], 1);
    eid[p] = e;
  }
}

// ---------------- weight/tiles prep (f32 -> bf16 once per call) ----------------
__global__ void k_wprep(const float* __restrict__ Wih, const float* __restrict__ Whh,
                        const float* __restrict__ Wl, const float* __restrict__ Wr,
                        const float* __restrict__ Win, const float* __restrict__ Wout,
                        const float* __restrict__ tiles,
                        const float* __restrict__ bl, const float* __restrict__ br,
                        unsigned short* __restrict__ wbuf, unsigned short* __restrict__ tilesb,
                        float* __restrict__ blrc){
  int i = blockIdx.x * 256 + threadIdx.x;
  if (i < 49152){ wbuf[i] = f2bf(Wih[i]); }
  else if (i < 98304){ int j = i - 49152; wbuf[49152 + j] = f2bf(Whh[j]); }
  else if (i < 229376){
    int j = i - 98304;
    int l = j >> 15, rem = j & 32767, m = rem >> 7, k = rem & 127;
    float v = (m < 128) ? Wl[l * 16384 + m * 128 + k] : Wr[l * 16384 + (m - 128) * 128 + k];
    wbuf[98304 + j] = f2bf(v);
  }
  else if (i < 278528){ int j = i - 229376; wbuf[229376 + j] = f2bf(Win[j]); }
  else if (i < 294912){ int j = i - 278528; wbuf[278528 + j] = f2bf(Wout[j]); }
  else if (i < 819200){ int j = i - 294912; tilesb[j] = f2bf(tiles[j]); }
  else if (i < 820224){
    int j = i - 819200;
    int l = j >> 8, m = j & 255;
    blrc[j] = (m < 128) ? bl[l * 128 + m] : br[l * 128 + m - 128];
  }
}

// f32 [NN*HH] -> bf16, 4 elems/thread
__global__ void k_h2b(const float* __restrict__ src, unsigned short* __restrict__ dst){
  int i = blockIdx.x * 256 + threadIdx.x;
  int base = i * 4;
  float4 v = *(const float4*)(src + base);
  unsigned v01 = (unsigned)f2bf(v.x) | ((unsigned)f2bf(v.y) << 16);
  unsigned v23 = (unsigned)f2bf(v.z) | ((unsigned)f2bf(v.w) << 16);
  uint2 p; p.x = v01; p.y = v23;
  *(uint2*)(dst + base) = p;
}

// ---------------- generic MFMA projection: Y[n][m] = bias[m] + sum_k Xb[n][k]*Wb[m][k]
// K=128. grid (NN/64, MTOT/128), 256 threads = 4 waves; wave w owns node rows [16w,16w+16).
template<int MTOT>
__global__ __launch_bounds__(256) void k_lin(const unsigned short* __restrict__ Xb,
                                             const unsigned short* __restrict__ Wb,
                                             const float* __restrict__ bias,
                                             float* __restrict__ Y){
  __shared__ __align__(16) unsigned short Xs[64 * XSTR];
  int t = threadIdx.x;
  int n0 = blockIdx.x * 64;
  int m0 = blockIdx.y * 128;
  // stage X tile (64x128 bf16) via uint4
  #pragma unroll
  for (int k2 = 0; k2 < 4; k2++){
    int v = t + k2 * 256;
    int r = v >> 4, c8 = v & 15;
    *(uint4*)(Xs + r * XSTR + c8 * 8) = *(const uint4*)(Xb + (n0 + r) * 128 + c8 * 8);
  }
  __syncthreads();
  int ln = t & 63, w = t >> 6, lm = ln & 15, quad = ln >> 4;
  const unsigned short* abase = Xs + (16 * w + lm) * XSTR + quad * 8;
  const unsigned short* bbase = Wb + (m0 + lm) * 128 + quad * 8;
  union { uint4 u; bf16x8 v; } af[4];
  #pragma unroll
  for (int ks = 0; ks < 4; ks++) af[ks].u = *(const uint4*)(abase + ks * 32);
  f32x4 acc[8];
  #pragma unroll
  for (int i = 0; i < 8; i++) acc[i] = (f32x4){0.f, 0.f, 0.f, 0.f};
  #pragma unroll
  for (int t2 = 0; t2 < 8; t2++){
    #pragma unroll
    for (int ks = 0; ks < 4; ks++){
      union { uint4 u; bf16x8 v; } bu;
      bu.u = *(const uint4*)(bbase + t2 * 16 * 128 + ks * 32);
      acc[t2] = __builtin_amdgcn_mfma_f32_16x16x32_bf16(af[ks].v, bu.v, acc[t2], 0, 0, 0);
    }
  }
  #pragma unroll
  for (int t2 = 0; t2 < 8; t2++){
    float bv = bias[m0 + t2 * 16 + lm];
    #pragma unroll
    for (int r = 0; r < 4; r++){
      Y[(n0 + 16 * w + quad * 4 + r) * MTOT + m0 + t2 * 16 + lm] = acc[t2][r] + bv;
    }
  }
}

// ---------------- encoders ----------------
__global__ void k_ue(const float* __restrict__ u, const float* __restrict__ W,
                     const float* __restrict__ b, const float* __restrict__ g,
                     const float* __restrict__ be, float* __restrict__ ue){
  __shared__ float red[128];
  __shared__ float us[GFEAT];
  int j = threadIdx.x;
  if (j < GFEAT) us[j] = u[j];
  __syncthreads();
  float acc = b[j];
  #pragma unroll
  for (int k = 0; k < GFEAT; k++) acc += us[k] * W[j * GFEAT + k];
  float mu = block_sum128(acc, red) * (1.0f / HH);
  float d = acc - mu;
  float var = block_sum128(d * d, red) * (1.0f / HH);
  ue[j] = gelu_f(d * rsqrtf(var + 1e-5f) * g[j] + be[j]);
}

__global__ void k_node_enc(const float* __restrict__ x, const float* __restrict__ tf,
                           const float* __restrict__ W, const float* __restrict__ b,
                           const float* __restrict__ g, const float* __restrict__ be,
                           const float* __restrict__ ue, float* __restrict__ h){
  __shared__ float red[128];
  __shared__ float xs[NFEAT + 1];
  int n = blockIdx.x, j = threadIdx.x;
  if (j < NFEAT) xs[j] = x[n * NFEAT + j];
  if (j == NFEAT) xs[NFEAT] = tf[0];
  __syncthreads();
  float acc = b[j];
  #pragma unroll
  for (int k = 0; k < NFEAT + 1; k++) acc += xs[k] * W[j * (NFEAT + 1) + k];
  float mu = block_sum128(acc, red) * (1.0f / HH);
  float d = acc - mu;
  float var = block_sum128(d * d, red) * (1.0f / HH);
  h[n * HH + j] = gelu_f(d * rsqrtf(var + 1e-5f) * g[j] + be[j]) + ue[j];
}

// ---------------- GRU combine (gi, gh already have biases) ----------------
__global__ void k_gru_comb(const float* __restrict__ gi, const float* __restrict__ gh,
                           const float* __restrict__ tiles, float* __restrict__ h,
                           float* __restrict__ out_tiles){
  int idx = blockIdx.x * 256 + threadIdx.x;
  int n = idx >> 7, j = idx & 127;
  float ir = gi[n * 384 + j], iz = gi[n * 384 + 128 + j], inn = gi[n * 384 + 256 + j];
  float hr = gh[n * 384 + j], hz = gh[n * 384 + 128 + j], hn = gh[n * 384 + 256 + j];
  float r = sigm(ir + hr), z = sigm(iz + hz);
  float nn2 = tanhf(inn + r * hn);
  float ts = tiles[idx];
  float hnew = (1.0f - z) * nn2 + z * ts;
  h[idx] = hnew;
  out_tiles[idx] = hnew;
}

// ---------------- GATv2 edge pieces (xlr: [N][256] = xl||xr, biases included) ----------------
__global__ void k_score(const int* __restrict__ ei, const float* __restrict__ ea,
                        const float* __restrict__ xlr,
                        const float* __restrict__ We, const float* __restrict__ att,
                        float* __restrict__ ex){
  int e = blockIdx.x * 256 + threadIdx.x;
  if (e >= EE) return;
  int s = ei[e], d = ei[EE + e];
  float a0 = ea[e * 4], a1 = ea[e * 4 + 1], a2 = ea[e * 4 + 2], a3 = ea[e * 4 + 3];
  const float* xls = &xlr[s * 256];
  const float* xrd = &xlr[d * 256 + 128];
  #pragma unroll
  for (int hh = 0; hh < NHEADS; hh++){
    float sc = 0.0f;
    #pragma unroll
    for (int dd = 0; dd < HDIM; dd++){
      int j = hh * HDIM + dd;
      float eev = a0 * We[j * 4] + a1 * We[j * 4 + 1] + a2 * We[j * 4 + 2] + a3 * We[j * 4 + 3];
      float v = xls[j] + xrd[j] + eev;
      v = v > 0.0f ? v : 0.2f * v;
      sc += v * att[j];
    }
    ex[e * 4 + hh] = expf(sc);
  }
}

__global__ void k_aggln(const float* __restrict__ xlr, const float* __restrict__ ex,
                        const int* __restrict__ off, const int* __restrict__ eid,
                        const int* __restrict__ ei,
                        const float* __restrict__ bias, const float* __restrict__ g,
                        const float* __restrict__ b, float* __restrict__ h){
  __shared__ float red[128];
  __shared__ float den[NHEADS];
  int n = blockIdx.x, j = threadIdx.x;
  int p0 = off[n], p1 = off[n + 1];
  if (j < NHEADS){
    float s = 0.0f;
    for (int p = p0; p < p1; p++) s += ex[eid[p] * 4 + j];
    den[j] = s;
  }
  __syncthreads();
  int hh = j >> 5;
  float dinv = 1.0f / (den[hh] + 1e-16f);
  float agg = 0.0f;
  for (int p = p0; p < p1; p++){
    int e = eid[p];
    int s = ei[e];
    agg += ex[e * 4 + hh] * xlr[s * 256 + j];
  }
  agg *= dinv;
  float val = h[n * HH + j] + agg + bias[j];
  float mu = block_sum128(val, red) * (1.0f / HH);
  float d2 = val - mu;
  float var = block_sum128(d2 * d2, red) * (1.0f / HH);
  h[n * HH + j] = d2 * rsqrtf(var + 1e-5f) * g[j] + b[j];
}

// ---------------- global attention ----------------
// qkvf [N][384] f32 (bias incl) -> qb/kb bf16 [N][128], vt bf16 [128][N]
__global__ __launch_bounds__(256) void k_qkv_post(const float* __restrict__ qkvf,
                                                  unsigned short* __restrict__ qb,
                                                  unsigned short* __restrict__ kb,
                                                  unsigned short* __restrict__ vt){
  __shared__ unsigned short Vls[128 * 66];
  int t = threadIdx.x;
  int n0 = blockIdx.x * 64;
  for (int idx = t; idx < 64 * 384; idx += 256){
    int nl = idx / 384, col = idx - nl * 384;
    unsigned short bv = f2bf(qkvf[(n0 + nl) * 384 + col]);
    if (col < 128) qb[(n0 + nl) * 128 + col] = bv;
    else if (col < 256) kb[(n0 + nl) * 128 + col - 128] = bv;
    else Vls[(col - 256) * 66 + nl] = bv;
  }
  __syncthreads();
  for (int idx = t; idx < 128 * 64; idx += 256){
    int j = idx >> 6, nl = idx & 63;
    vt[j * NN + n0 + nl] = Vls[j * 66 + nl];
  }
}

#define PSTR 40
__global__ __launch_bounds__(256) void k_attn_flash(
    const unsigned short* __restrict__ qb, const unsigned short* __restrict__ kb,
    const unsigned short* __restrict__ vt,
    float* __restrict__ pden, float* __restrict__ pacc){
  __shared__ __align__(16) unsigned short Pl[4][16 * PSTR];
  int t = threadIdx.x, w = t >> 6, ln = t & 63;
  int c = ln & 15, qd = ln >> 4;
  int hh = blockIdx.y, ks = blockIdx.z;
  int q0 = blockIdx.x * 64 + w * 16;
  union { uint4 u; bf16x8 v; } qf;
  qf.u = *(const uint4*)(qb + (q0 + c) * HH + hh * HDIM + qd * 8);
  f32x4 o0 = {0.f,0.f,0.f,0.f}, o1 = {0.f,0.f,0.f,0.f};
  float denp = 0.f;
  const float scale = 0.17677669529663687f;
  unsigned short* P = &Pl[w][0];
  const unsigned short* vrow0 = vt + (hh * HDIM + c) * NN;
  const unsigned short* vrow1 = vt + (hh * HDIM + 16 + c) * NN;
  for (int k0 = ks * (NN / KS); k0 < (ks + 1) * (NN / KS); k0 += 32){
    #pragma unroll
    for (int tt = 0; tt < 2; tt++){
      union { uint4 u; bf16x8 v; } kf;
      kf.u = *(const uint4*)(kb + (k0 + tt * 16 + c) * HH + hh * HDIM + qd * 8);
      f32x4 s = {0.f,0.f,0.f,0.f};
      s = __builtin_amdgcn_mfma_f32_16x16x32_bf16(kf.v, qf.v, s, 0, 0, 0);
      float e0 = expf(s[0] * scale), e1 = expf(s[1] * scale);
      float e2 = expf(s[2] * scale), e3 = expf(s[3] * scale);
      denp += (e0 + e1) + (e2 + e3);
      unsigned p01 = (unsigned)f2bf(e0) | ((unsigned)f2bf(e1) << 16);
      unsigned p23 = (unsigned)f2bf(e2) | ((unsigned)f2bf(e3) << 16);
      *(unsigned*)(P + c * PSTR + tt * 16 + qd * 4)     = p01;
      *(unsigned*)(P + c * PSTR + tt * 16 + qd * 4 + 2) = p23;
    }
    union { uint4 u; bf16x8 v; } af, b0, b1;
    af.u = *(const uint4*)(P + c * PSTR + qd * 8);
    b0.u = *(const uint4*)(vrow0 + k0 + qd * 8);
    b1.u = *(const uint4*)(vrow1 + k0 + qd * 8);
    o0 = __builtin_amdgcn_mfma_f32_16x16x32_bf16(af.v, b0.v, o0, 0, 0, 0);
    o1 = __builtin_amdgcn_mfma_f32_16x16x32_bf16(af.v, b1.v, o1, 0, 0, 0);
  }
  denp += __shfl_xor(denp, 16);
  denp += __shfl_xor(denp, 32);
  if (qd == 0) pden[((q0 + c) * NHEADS + hh) * KS + ks] = denp;
  #pragma unroll
  for (int r = 0; r < 4; r++){
    int qn = q0 + qd * 4 + r;
    int pi = (qn * NHEADS + hh) * KS + ks;
    pacc[pi * HDIM + c]      = o0[r];
    pacc[pi * HDIM + 16 + c] = o1[r];
  }
}

// combine key-split partials -> aob bf16 [N][128]
__global__ void k_attn_comb(const float* __restrict__ pden, const float* __restrict__ pacc,
                            unsigned short* __restrict__ aob){
  int n = blockIdx.x, j = threadIdx.x;
  int hh = j >> 5, d = j & 31;
  float ds = 0.0f, as = 0.0f;
  #pragma unroll
  for (int ks = 0; ks < KS; ks++){
    int pi = (n * NHEADS + hh) * KS + ks;
    ds += pden[pi];
    as += pacc[pi * HDIM + d];
  }
  aob[n * HH + j] = f2bf(as / ds);
}

// h = LN(h + proj; g,b)
__global__ void k_resln(const float* __restrict__ proj, const float* __restrict__ g,
                        const float* __restrict__ b, float* __restrict__ h){
  __shared__ float red[128];
  int n = blockIdx.x, j = threadIdx.x;
  float val = h[n * HH + j] + proj[n * HH + j];
  float mu = block_sum128(val, red) * (1.0f / HH);
  float dd = val - mu;
  float var = block_sum128(dd * dd, red) * (1.0f / HH);
  h[n * HH + j] = dd * rsqrtf(var + 1e-5f) * g[j] + b[j];
}

// ---------------- bf16 prep for edge heads ----------------
__global__ void k_prep(const float* __restrict__ h, const float* __restrict__ ea,
                       const float* __restrict__ mvW1, const float* __restrict__ frW1,
                       unsigned short* __restrict__ hb, unsigned short* __restrict__ eab,
                       unsigned short* __restrict__ wb){
  int idx = blockIdx.x * 256 + threadIdx.x;
  if (idx < NN * HH){
    hb[idx] = f2bf(h[idx]);
  } else if (idx < NN * HH + EE * 4){
    int i = idx - NN * HH;
    eab[i] = f2bf(ea[i]);
  } else {
    int i = idx - (NN * HH + EE * 4);
    if (i < 256 * KPAD){
      int n = i / KPAD, k = i - n * KPAD;
      float v = 0.0f;
      if (k < 2 * HH + EFEAT) v = (n < HH) ? mvW1[n * (2 * HH + EFEAT) + k]
                                           : frW1[(n - HH) * (2 * HH + EFEAT) + k];
      wb[i] = f2bf(v);
    }
  }
}

// ---------------- edge heads via MFMA ----------------
__global__ __launch_bounds__(256) void k_edge_mfma(
    const unsigned short* __restrict__ hb, const unsigned short* __restrict__ eab,
    const int* __restrict__ ei, const unsigned short* __restrict__ wb,
    const float* __restrict__ mvb1, const float* __restrict__ frb1,
    const float* __restrict__ mvW2, const float* __restrict__ mvb2,
    const float* __restrict__ frW2, const float* __restrict__ frb2,
    float* __restrict__ out){
  __shared__ __align__(16) unsigned short As[64 * KPAD];
  int t = threadIdx.x;
  int e0 = blockIdx.x * 64;
  {
    int el = t >> 2, p = t & 3;
    int e = e0 + el;
    int node = (p < 2) ? ei[e] : ei[EE + e];
    int half = p & 1;
    const uint4* srcp = (const uint4*)(hb + node * HH + half * 64);
    uint4* dstp = (uint4*)(As + el * KPAD + (p >> 1) * 128 + half * 64);
    #pragma unroll
    for (int i = 0; i < 8; i++) dstp[i] = srcp[i];
    if (p == 0){
      unsigned short* tail = As + el * KPAD + 256;
      tail[0] = eab[e * 4];     tail[1] = eab[e * 4 + 1];
      tail[2] = eab[e * 4 + 2]; tail[3] = eab[e * 4 + 3];
      #pragma unroll
      for (int i = 4; i < KPAD - 256; i++) tail[i] = 0;
    }
  }
  int ln = t & 63, w = t >> 6;
  int lm = ln & 15, quad = ln >> 4;
  const unsigned short* abase = As + (16 * w + lm) * KPAD + quad * 8;
  const unsigned short* bbase = wb + lm * KPAD + quad * 8;
  f32x4 acc[16];
  #pragma unroll
  for (int i = 0; i < 16; i++) acc[i] = (f32x4){0.f, 0.f, 0.f, 0.f};
  __syncthreads();
  for (int ks = 0; ks < 9; ks++){
    union { uint4 u; bf16x8 v; } au;
    au.u = *(const uint4*)(abase + ks * 32);
    #pragma unroll
    for (int t2 = 0; t2 < 16; t2++){
      union { uint4 u; bf16x8 v; } bu;
      bu.u = *(const uint4*)(bbase + t2 * 16 * KPAD + ks * 32);
      acc[t2] = __builtin_amdgcn_mfma_f32_16x16x32_bf16(au.v, bu.v, acc[t2], 0, 0, 0);
    }
  }
  float sm[4] = {0.f, 0.f, 0.f, 0.f};
  float s0[4] = {0.f, 0.f, 0.f, 0.f};
  float s1[4] = {0.f, 0.f, 0.f, 0.f};
  #pragma unroll
  for (int t2 = 0; t2 < 16; t2++){
    int n = 16 * t2 + lm;
    float b1v, w2m, w20, w21;
    if (n < HH){ b1v = mvb1[n]; w2m = mvW2[n]; w20 = 0.f; w21 = 0.f; }
    else { int j = n - HH; b1v = frb1[j]; w2m = 0.f; w20 = frW2[j]; w21 = frW2[HH + j]; }
    #pragma unroll
    for (int r = 0; r < 4; r++){
      float g = gelu_f(acc[t2][r] + b1v);
      sm[r] += g * w2m; s0[r] += g * w20; s1[r] += g * w21;
    }
  }
  #pragma unroll
  for (int d = 1; d < 16; d <<= 1){
    #pragma unroll
    for (int r = 0; r < 4; r++){
      sm[r] += __shfl_xor(sm[r], d);
      s0[r] += __shfl_xor(s0[r], d);
      s1[r] += __shfl_xor(s1[r], d);
    }
  }
  if (lm == 0){
    #pragma unroll
    for (int r = 0; r < 4; r++){
      int e = e0 + 16 * w + 4 * quad + r;
      out[e]          = sm[r] + mvb2[0];
      out[EE + e]     = softplus_f(s0[r] + frb2[0]) + 1e-4f;
      out[2 * EE + e] = softplus_f(s1[r] + frb2[1]) + 1e-4f;
    }
  }
}

// ---------------- value head ----------------
__global__ void k_pool(const float* __restrict__ h, const unsigned char* __restrict__ mask,
                       float* __restrict__ gsum, float* __restrict__ msum, float* __restrict__ mcnt){
  int bb = blockIdx.x, j = threadIdx.x;
  float ga = 0.0f, ma = 0.0f;
  int n0 = bb * 32;
  for (int i = 0; i < 32; i++){
    int n = n0 + i;
    float v = h[n * HH + j];
    ga += v;
    if (mask[n]) ma += v;
  }
  atomicAdd(&gsum[j], ga);
  atomicAdd(&msum[j], ma);
  if (j == 0){
    float c = 0.0f;
    for (int i = 0; i < 32; i++) c += mask[n0 + i] ? 1.0f : 0.0f;
    atomicAdd(mcnt, c);
  }
}

__global__ void k_value(const float* __restrict__ gsum, const float* __restrict__ msum,
                        const float* __restrict__ mcnt,
                        const float* __restrict__ W1, const float* __restrict__ b1,
                        const float* __restrict__ W2, const float* __restrict__ b2,
                        float* __restrict__ out_val){
  __shared__ float red[128];
  __shared__ float vin[256];
  int j = threadIdx.x;
  float gp = gsum[j] * (1.0f / NN);
  float as = msum[j] * (1.0f / NN);
  float ac = fmaxf(mcnt[0] * (1.0f / NN), 1e-6f);
  vin[j] = gp; vin[HH + j] = as / ac;
  __syncthreads();
  float acc = b1[j];
  const float* w = &W1[j * 256];
  #pragma unroll 4
  for (int k = 0; k < 256; k++) acc += vin[k] * w[k];
  float hv = gelu_f(acc) * W2[j];
  float s = block_sum128(hv, red);
  if (j == 0) out_val[0] = s + b2[0];
}

extern "C" void kernel_launch(void* const* d_in, const int* in_sizes, int n_in,
                              void* d_out, int out_size, void* d_ws, size_t ws_size,
                              hipStream_t stream){
  (void)in_sizes; (void)n_in; (void)out_size; (void)ws_size;
  const float* x        = (const float*)d_in[0];
  const int*   ei       = (const int*)d_in[1];
  const float* ea       = (const float*)d_in[2];
  const float* u        = (const float*)d_in[3];
  const unsigned char* mask = (const unsigned char*)d_in[4];
  const float* tiles    = (const float*)d_in[5];
  const float* tf       = (const float*)d_in[7];
  const float* ne_W  = (const float*)d_in[8];
  const float* ne_b  = (const float*)d_in[9];
  const float* ne_g  = (const float*)d_in[10];
  const float* ne_be = (const float*)d_in[11];
  const float* ge_W  = (const float*)d_in[12];
  const float* ge_b  = (const float*)d_in[13];
  const float* ge_g  = (const float*)d_in[14];
  const float* ge_be = (const float*)d_in[15];
  const float* gru_Wih = (const float*)d_in[16];
  const float* gru_bih = (const float*)d_in[17];
  const float* gru_Whh = (const float*)d_in[18];
  const float* gru_bhh = (const float*)d_in[19];
  const float* gat_Wl  = (const float*)d_in[20];
  const float* gat_bl  = (const float*)d_in[21];
  const float* gat_Wr  = (const float*)d_in[22];
  const float* gat_br  = (const float*)d_in[23];
  const float* gat_We  = (const float*)d_in[24];
  const float* gat_att = (const float*)d_in[25];
  const float* gat_bias= (const float*)d_in[26];
  const float* ln_g    = (const float*)d_in[27];
  const float* ln_b    = (const float*)d_in[28];
  const float* attn_Win = (const float*)d_in[29];
  const float* attn_bin = (const float*)d_in[30];
  const float* attn_Wout= (const float*)d_in[31];
  const float* attn_bout= (const float*)d_in[32];
  const float* lng_g    = (const float*)d_in[33];
  const float* lng_b    = (const float*)d_in[34];
  const float* mv_W1 = (const float*)d_in[35];
  const float* mv_b1 = (const float*)d_in[36];
  const float* mv_W2 = (const float*)d_in[37];
  const float* mv_b2 = (const float*)d_in[38];
  const float* fr_W1 = (const float*)d_in[39];
  const float* fr_b1 = (const float*)d_in[40];
  const float* fr_W2 = (const float*)d_in[41];
  const float* fr_b2 = (const float*)d_in[42];
  const float* vl_W1 = (const float*)d_in[43];
  const float* vl_b1 = (const float*)d_in[44];
  const float* vl_W2 = (const float*)d_in[45];
  const float* vl_b2 = (const float*)d_in[46];

  // ---- workspace layout (f32 elem offsets) ----
  float* ws = (float*)d_ws;
  float* h      = ws;                         // 524288
  float* xlr    = ws + 524288;                // 1048576 ([N][256])
  unsigned short* hb     = (unsigned short*)(ws + 1572864);  // NN*HH bf16
  unsigned short* tilesb = (unsigned short*)(ws + 1835008);  // NN*HH bf16
  unsigned short* wbuf   = (unsigned short*)(ws + 2097152);  // 294912 bf16
  unsigned short* Wihb  = wbuf;
  unsigned short* Whhb  = wbuf + 49152;
  unsigned short* Wlrb  = wbuf + 98304;   // [L][256][128]
  unsigned short* Winb  = wbuf + 229376;
  unsigned short* Woutb = wbuf + 278528;
  float* blrc   = ws + 2244608;               // [L][256] f32
  float* ue     = ws + 2245632;               // 128
  float* gsum   = ws + 2245760;               // 128
  float* msum   = ws + 2245888;               // 128
  float* mcnt   = ws + 2246016;               // 1 (+pad)
  int*   cnt    = (int*)(ws + 2246032);       // 4096
  int*   off    = cnt + NN;                   // 4097
  int*   cur    = off + NN + 1;               // 4096
  int*   eid    = cur + NN;                   // 65536
  float* S      = ws + 2323904;               // 3145728 scratch (multi-phase)
  // GRU phase:
  float* gi = S;                  // [N][384]
  float* gh = S + 1572864;        // [N][384]
  // GAT phase:
  float* ex = S;                  // [E][4]
  // attention phase:
  float* qkvf = S;                                    // [N][384]
  unsigned short* qb = (unsigned short*)(S + 1572864);
  unsigned short* kb = (unsigned short*)(S + 1835008);
  unsigned short* vt = (unsigned short*)(S + 2097152);
  float* pacc = S;                                    // 1048576 (after qkvf dead)
  float* pden = S + 1048576;                          // 32768
  unsigned short* aob = (unsigned short*)(S + 1081344); // NN*HH bf16
  float* aoproj = S + 1572864;                        // [N][128] f32 (after qb dead)
  // edge phase:
  unsigned short* hbE = (unsigned short*)S;
  unsigned short* eab = (unsigned short*)(S + 262144);
  unsigned short* wbE = (unsigned short*)(S + 393216);

  float* out       = (float*)d_out;
  float* out_val   = out + 3 * EE;
  float* out_tiles = out + 3 * EE + 1;

  // CSR of incoming edges
  hipMemsetAsync(cnt, 0, NN * sizeof(int), stream);
  k_hist   <<<EE / 256, 256, 0, stream>>>(ei, cnt);
  k_scan   <<<1, 256, 0, stream>>>(cnt, off, cur);
  k_scatter<<<EE / 256, 256, 0, stream>>>(ei, cur, eid);

  // weight prep
  k_wprep<<<(820224 + 255) / 256, 256, 0, stream>>>(gru_Wih, gru_Whh, gat_Wl, gat_Wr,
                                                    attn_Win, attn_Wout, tiles,
                                                    gat_bl, gat_br, wbuf, tilesb, blrc);

  // encoders
  k_ue      <<<1, 128, 0, stream>>>(u, ge_W, ge_b, ge_g, ge_be, ue);
  k_node_enc<<<NN, 128, 0, stream>>>(x, tf, ne_W, ne_b, ne_g, ne_be, ue, h);

  // GRU via MFMA
  k_h2b<<<512, 256, 0, stream>>>(h, hb);
  { dim3 g(NN / 64, 3);
    k_lin<384><<<g, 256, 0, stream>>>(hb, Wihb, gru_bih, gi);
    k_lin<384><<<g, 256, 0, stream>>>(tilesb, Whhb, gru_bhh, gh); }
  k_gru_comb<<<NN * HH / 256, 256, 0, stream>>>(gi, gh, tiles, h, out_tiles);

  // GATv2 stack
  for (int l = 0; l < NLAYERS; l++){
    k_h2b<<<512, 256, 0, stream>>>(h, hb);
    { dim3 g(NN / 64, 2);
      k_lin<256><<<g, 256, 0, stream>>>(hb, Wlrb + l * 32768, blrc + l * 256, xlr); }
    k_score<<<EE / 256, 256, 0, stream>>>(ei, ea, xlr,
                                          gat_We + l * HH * EFEAT,
                                          gat_att + l * NHEADS * HDIM, ex);
    k_aggln<<<NN, 128, 0, stream>>>(xlr, ex, off, eid, ei,
                                    gat_bias + l * HH, ln_g + l * HH, ln_b + l * HH, h);
  }

  // global attention
  k_h2b<<<512, 256, 0, stream>>>(h, hb);
  { dim3 g(NN / 64, 3);
    k_lin<384><<<g, 256, 0, stream>>>(hb, Winb, attn_bin, qkvf); }
  k_qkv_post<<<NN / 64, 256, 0, stream>>>(qkvf, qb, kb, vt);
  { dim3 gattn(NN / 64, NHEADS, KS);
    k_attn_flash<<<gattn, 256, 0, stream>>>(qb, kb, vt, pden, pacc); }
  k_attn_comb<<<NN, 128, 0, stream>>>(pden, pacc, aob);
  { dim3 g(NN / 64, 1);
    k_lin<128><<<g, 256, 0, stream>>>(aob, Woutb, attn_bout, aoproj); }
  k_resln<<<NN, 128, 0, stream>>>(aoproj, lng_g, lng_b, h);

  // edge heads (bf16 MFMA)
  {
    int total = NN * HH + EE * 4 + 256 * KPAD;
    k_prep<<<(total + 255) / 256, 256, 0, stream>>>(h, ea, mv_W1, fr_W1, hbE, eab, wbE);
    k_edge_mfma<<<EE / 64, 256, 0, stream>>>(hbE, eab, ei, wbE, mv_b1, fr_b1,
                                             mv_W2, mv_b2, fr_W2, fr_b2, out);
  }

  // value head
  hipMemsetAsync(gsum, 0, 257 * sizeof(float), stream);
  k_pool <<<128, 128, 0, stream>>>(h, mask, gsum, msum, mcnt);
  k_value<<<1, 128, 0, stream>>>(gsum, msum, mcnt, vl_W1, vl_b1, vl_W2, vl_b2, out_val);
}

// Round 5
// 499.210 us; speedup vs baseline: 4.7865x; 1.2867x over previous
//
#include <hip/hip_runtime.h>
#include <math.h>

// StrategistGNN forward on MI355X. Round 5: col-split edge-head GEMM (4x fewer
// B loads), vectorized GAT score, parallel-den aggln, fused bf16 conversions.
// N=4096 nodes, E=65536 edges, H=128, 4 heads x 32, L=4 GAT layers, B=1.

#define NN 4096
#define EE 65536
#define HH 128
#define NHEADS 4
#define HDIM 32
#define NLAYERS 4
#define NFEAT 16
#define GFEAT 8
#define EFEAT 4
#define KS 2     // key-splits for global attention
#define KPAD 296 // padded K stride (bf16) for edge-head GEMM
#define XSTR 136 // k_lin LDS row stride (bf16): 2-way bank aliasing only (free)
#define PSTR 40

typedef short bf16x8 __attribute__((ext_vector_type(8)));
typedef float f32x4  __attribute__((ext_vector_type(4)));

__device__ __forceinline__ float gelu_f(float x){
  return 0.5f * x * (1.0f + erff(x * 0.7071067811865475f));
}
__device__ __forceinline__ float sigm(float x){ return 1.0f / (1.0f + expf(-x)); }
__device__ __forceinline__ float softplus_f(float x){ return x > 20.0f ? x : log1pf(expf(x)); }
__device__ __forceinline__ unsigned short f2bf(float x){
  unsigned u = __float_as_uint(x);
  unsigned r = (u + 0x7FFFu + ((u >> 16) & 1u)) >> 16;
  return (unsigned short)r;
}

__device__ __forceinline__ float block_sum128(float v, float* red){
  int j = threadIdx.x;
  red[j] = v; __syncthreads();
  for (int s = 64; s > 0; s >>= 1){
    if (j < s) red[j] += red[j + s];
    __syncthreads();
  }
  float r = red[0];
  __syncthreads();
  return r;
}

// ---------------- CSR build ----------------
__global__ void k_hist(const int* __restrict__ ei, int* __restrict__ cnt){
  int e = blockIdx.x * 256 + threadIdx.x;
  if (e < EE) atomicAdd(&cnt[ei[EE + e]], 1);
}

__global__ void k_scan(const int* __restrict__ cnt, int* __restrict__ off, int* __restrict__ cur){
  __shared__ int part[256];
  int t = threadIdx.x;
  int local[16];
  int s = 0;
  #pragma unroll
  for (int i = 0; i < 16; i++){ local[i] = s; s += cnt[t * 16 + i]; }
  part[t] = s; __syncthreads();
  for (int o = 1; o < 256; o <<= 1){
    int v = (t >= o) ? part[t - o] : 0;
    __syncthreads();
    part[t] += v;
    __syncthreads();
  }
  int base = part[t] - s;
  #pragma unroll
  for (int i = 0; i < 16; i++){ int o = base + local[i]; off[t * 16 + i] = o; cur[t * 16 + i] = o; }
  if (t == 255) off[NN] = part[255];
}

__global__ void k_scatter(const int* __restrict__ ei, int* __restrict__ cur, int* __restrict__ eid){
  int e = blockIdx.x * 256 + threadIdx.x;
  if (e < EE){
    int d = ei[EE + e];
    int p = atomicAdd(&cur[d], 1);
    eid[p] = e;
  }
}

// ---------------- one-shot prep: weights/tiles/edge_attr -> bf16 ----------------
__global__ void k_wprep(const float* __restrict__ Wih, const float* __restrict__ Whh,
                        const float* __restrict__ Wl, const float* __restrict__ Wr,
                        const float* __restrict__ Win, const float* __restrict__ Wout,
                        const float* __restrict__ tiles,
                        const float* __restrict__ bl, const float* __restrict__ br,
                        const float* __restrict__ ea,
                        const float* __restrict__ mvW1, const float* __restrict__ frW1,
                        unsigned short* __restrict__ wbuf, unsigned short* __restrict__ tilesb,
                        float* __restrict__ blrc,
                        unsigned short* __restrict__ wbE, unsigned short* __restrict__ eab){
  int i = blockIdx.x * 256 + threadIdx.x;
  if (i < 49152){ wbuf[i] = f2bf(Wih[i]); }
  else if (i < 98304){ int j = i - 49152; wbuf[49152 + j] = f2bf(Whh[j]); }
  else if (i < 229376){
    int j = i - 98304;
    int l = j >> 15, rem = j & 32767, m = rem >> 7, k = rem & 127;
    float v = (m < 128) ? Wl[l * 16384 + m * 128 + k] : Wr[l * 16384 + (m - 128) * 128 + k];
    wbuf[98304 + j] = f2bf(v);
  }
  else if (i < 278528){ int j = i - 229376; wbuf[229376 + j] = f2bf(Win[j]); }
  else if (i < 294912){ int j = i - 278528; wbuf[278528 + j] = f2bf(Wout[j]); }
  else if (i < 819200){ int j = i - 294912; tilesb[j] = f2bf(tiles[j]); }
  else if (i < 820224){
    int j = i - 819200;
    int l = j >> 8, m = j & 255;
    blrc[j] = (m < 128) ? bl[l * 128 + m] : br[l * 128 + m - 128];
  }
  else if (i < 896000){
    int j = i - 820224;                 // wbE: [256][KPAD], zero-padded 260->KPAD
    int n = j / KPAD, k = j - n * KPAD;
    float v = 0.0f;
    if (k < 2 * HH + EFEAT) v = (n < HH) ? mvW1[n * (2 * HH + EFEAT) + k]
                                         : frW1[(n - HH) * (2 * HH + EFEAT) + k];
    wbE[j] = f2bf(v);
  }
  else if (i < 1158144){
    int j = i - 896000;                 // eab
    eab[j] = f2bf(ea[j]);
  }
}

// ---------------- generic MFMA projection: Y[n][m] = bias[m] + sum_k Xb[n][k]*Wb[m][k]
template<int MTOT>
__global__ __launch_bounds__(256) void k_lin(const unsigned short* __restrict__ Xb,
                                             const unsigned short* __restrict__ Wb,
                                             const float* __restrict__ bias,
                                             float* __restrict__ Y){
  __shared__ __align__(16) unsigned short Xs[64 * XSTR];
  int t = threadIdx.x;
  int n0 = blockIdx.x * 64;
  int m0 = blockIdx.y * 128;
  #pragma unroll
  for (int k2 = 0; k2 < 4; k2++){
    int v = t + k2 * 256;
    int r = v >> 4, c8 = v & 15;
    *(uint4*)(Xs + r * XSTR + c8 * 8) = *(const uint4*)(Xb + (n0 + r) * 128 + c8 * 8);
  }
  __syncthreads();
  int ln = t & 63, w = t >> 6, lm = ln & 15, quad = ln >> 4;
  const unsigned short* abase = Xs + (16 * w + lm) * XSTR + quad * 8;
  const unsigned short* bbase = Wb + (m0 + lm) * 128 + quad * 8;
  union { uint4 u; bf16x8 v; } af[4];
  #pragma unroll
  for (int ks = 0; ks < 4; ks++) af[ks].u = *(const uint4*)(abase + ks * 32);
  f32x4 acc[8];
  #pragma unroll
  for (int i = 0; i < 8; i++) acc[i] = (f32x4){0.f, 0.f, 0.f, 0.f};
  #pragma unroll
  for (int t2 = 0; t2 < 8; t2++){
    #pragma unroll
    for (int ks = 0; ks < 4; ks++){
      union { uint4 u; bf16x8 v; } bu;
      bu.u = *(const uint4*)(bbase + t2 * 16 * 128 + ks * 32);
      acc[t2] = __builtin_amdgcn_mfma_f32_16x16x32_bf16(af[ks].v, bu.v, acc[t2], 0, 0, 0);
    }
  }
  #pragma unroll
  for (int t2 = 0; t2 < 8; t2++){
    float bv = bias[m0 + t2 * 16 + lm];
    #pragma unroll
    for (int r = 0; r < 4; r++){
      Y[(n0 + 16 * w + quad * 4 + r) * MTOT + m0 + t2 * 16 + lm] = acc[t2][r] + bv;
    }
  }
}

// ---------------- encoders ----------------
__global__ void k_ue(const float* __restrict__ u, const float* __restrict__ W,
                     const float* __restrict__ b, const float* __restrict__ g,
                     const float* __restrict__ be, float* __restrict__ ue){
  __shared__ float red[128];
  __shared__ float us[GFEAT];
  int j = threadIdx.x;
  if (j < GFEAT) us[j] = u[j];
  __syncthreads();
  float acc = b[j];
  #pragma unroll
  for (int k = 0; k < GFEAT; k++) acc += us[k] * W[j * GFEAT + k];
  float mu = block_sum128(acc, red) * (1.0f / HH);
  float d = acc - mu;
  float var = block_sum128(d * d, red) * (1.0f / HH);
  ue[j] = gelu_f(d * rsqrtf(var + 1e-5f) * g[j] + be[j]);
}

__global__ void k_node_enc(const float* __restrict__ x, const float* __restrict__ tf,
                           const float* __restrict__ W, const float* __restrict__ b,
                           const float* __restrict__ g, const float* __restrict__ be,
                           const float* __restrict__ ue, float* __restrict__ h,
                           unsigned short* __restrict__ hb){
  __shared__ float red[128];
  __shared__ float xs[NFEAT + 1];
  int n = blockIdx.x, j = threadIdx.x;
  if (j < NFEAT) xs[j] = x[n * NFEAT + j];
  if (j == NFEAT) xs[NFEAT] = tf[0];
  __syncthreads();
  float acc = b[j];
  #pragma unroll
  for (int k = 0; k < NFEAT + 1; k++) acc += xs[k] * W[j * (NFEAT + 1) + k];
  float mu = block_sum128(acc, red) * (1.0f / HH);
  float d = acc - mu;
  float var = block_sum128(d * d, red) * (1.0f / HH);
  float r = gelu_f(d * rsqrtf(var + 1e-5f) * g[j] + be[j]) + ue[j];
  h[n * HH + j] = r;
  hb[n * HH + j] = f2bf(r);
}

// ---------------- GRU combine ----------------
__global__ void k_gru_comb(const float* __restrict__ gi, const float* __restrict__ gh,
                           const float* __restrict__ tiles, float* __restrict__ h,
                           unsigned short* __restrict__ hb, float* __restrict__ out_tiles){
  int idx = blockIdx.x * 256 + threadIdx.x;
  int n = idx >> 7, j = idx & 127;
  float ir = gi[n * 384 + j], iz = gi[n * 384 + 128 + j], inn = gi[n * 384 + 256 + j];
  float hr = gh[n * 384 + j], hz = gh[n * 384 + 128 + j], hn = gh[n * 384 + 256 + j];
  float r = sigm(ir + hr), z = sigm(iz + hz);
  float nn2 = tanhf(inn + r * hn);
  float ts = tiles[idx];
  float hnew = (1.0f - z) * nn2 + z * ts;
  h[idx] = hnew;
  hb[idx] = f2bf(hnew);
  out_tiles[idx] = hnew;
}

// ---------------- GAT score: 16 threads/edge, float4 loads, shfl head-reduce ----------------
__global__ __launch_bounds__(256) void k_score(const int* __restrict__ ei, const float* __restrict__ ea,
                        const float* __restrict__ xlr,
                        const float* __restrict__ We, const float* __restrict__ att,
                        float* __restrict__ ex){
  __shared__ float4 We4[128];
  __shared__ float atts[128];
  int t = threadIdx.x;
  if (t < 128){ We4[t] = ((const float4*)We)[t]; atts[t] = att[t]; }
  __syncthreads();
  int el = t >> 4, g = t & 15;
  int e = blockIdx.x * 16 + el;
  int s = ei[e], d = ei[EE + e];
  float4 a = *(const float4*)(ea + e * 4);
  float xls[8], xrs[8];
  *(float4*)(xls)     = *(const float4*)(xlr + s * 256 + g * 8);
  *(float4*)(xls + 4) = *(const float4*)(xlr + s * 256 + g * 8 + 4);
  *(float4*)(xrs)     = *(const float4*)(xlr + d * 256 + 128 + g * 8);
  *(float4*)(xrs + 4) = *(const float4*)(xlr + d * 256 + 128 + g * 8 + 4);
  float sc = 0.0f;
  #pragma unroll
  for (int i = 0; i < 8; i++){
    int j = g * 8 + i;
    float4 w = We4[j];
    float v = xls[i] + xrs[i] + a.x * w.x + a.y * w.y + a.z * w.z + a.w * w.w;
    v = v > 0.0f ? v : 0.2f * v;
    sc += v * atts[j];
  }
  sc += __shfl_xor(sc, 1);
  sc += __shfl_xor(sc, 2);
  if ((g & 3) == 0) ex[e * 4 + (g >> 2)] = expf(sc);
}

// ---------------- aggregate + residual + LN (parallel den, unrolled gather) ----------------
__global__ void k_aggln(const float* __restrict__ xlr, const float* __restrict__ ex,
                        const int* __restrict__ off, const int* __restrict__ eid,
                        const int* __restrict__ ei,
                        const float* __restrict__ bias, const float* __restrict__ g,
                        const float* __restrict__ b, float* __restrict__ h,
                        unsigned short* __restrict__ hb){
  __shared__ float red[128];
  __shared__ float den[NHEADS];
  int n = blockIdx.x, j = threadIdx.x;
  int p0 = off[n], p1 = off[n + 1];
  {
    int hh4 = j & 3, es = j >> 2;   // 32 edge slots x 4 heads
    float s = 0.0f;
    for (int p = p0 + es; p < p1; p += 32) s += ex[eid[p] * 4 + hh4];
    red[j] = s; __syncthreads();
    #pragma unroll
    for (int st = 16; st > 0; st >>= 1){
      if (es < st) red[j] += red[j + st * 4];
      __syncthreads();
    }
    if (j < 4) den[j] = red[j];
    __syncthreads();
  }
  int hh = j >> 5;
  float dinv = 1.0f / (den[hh] + 1e-16f);
  float agg = 0.0f;
  int p = p0;
  for (; p + 2 <= p1; p += 2){
    int e0 = eid[p], e1 = eid[p + 1];
    int s0 = ei[e0], s1 = ei[e1];
    float w0 = ex[e0 * 4 + hh], w1 = ex[e1 * 4 + hh];
    float x0 = xlr[s0 * 256 + j], x1 = xlr[s1 * 256 + j];
    agg += w0 * x0 + w1 * x1;
  }
  if (p < p1){ int e2 = eid[p]; agg += ex[e2 * 4 + hh] * xlr[ei[e2] * 256 + j]; }
  agg *= dinv;
  float val = h[n * HH + j] + agg + bias[j];
  float mu = block_sum128(val, red) * (1.0f / HH);
  float d2 = val - mu;
  float var = block_sum128(d2 * d2, red) * (1.0f / HH);
  float r = d2 * rsqrtf(var + 1e-5f) * g[j] + b[j];
  h[n * HH + j] = r;
  hb[n * HH + j] = f2bf(r);
}

// ---------------- global attention ----------------
__global__ __launch_bounds__(256) void k_qkv_post(const float* __restrict__ qkvf,
                                                  unsigned short* __restrict__ qb,
                                                  unsigned short* __restrict__ kb,
                                                  unsigned short* __restrict__ vt){
  __shared__ unsigned short Vls[128 * 66];
  int t = threadIdx.x;
  int n0 = blockIdx.x * 64;
  for (int idx = t; idx < 64 * 384; idx += 256){
    int nl = idx / 384, col = idx - nl * 384;
    unsigned short bv = f2bf(qkvf[(n0 + nl) * 384 + col]);
    if (col < 128) qb[(n0 + nl) * 128 + col] = bv;
    else if (col < 256) kb[(n0 + nl) * 128 + col - 128] = bv;
    else Vls[(col - 256) * 66 + nl] = bv;
  }
  __syncthreads();
  for (int idx = t; idx < 128 * 64; idx += 256){
    int j = idx >> 6, nl = idx & 63;
    vt[j * NN + n0 + nl] = Vls[j * 66 + nl];
  }
}

__global__ __launch_bounds__(256) void k_attn_flash(
    const unsigned short* __restrict__ qb, const unsigned short* __restrict__ kb,
    const unsigned short* __restrict__ vt,
    float* __restrict__ pden, float* __restrict__ pacc){
  __shared__ __align__(16) unsigned short Pl[4][16 * PSTR];
  int t = threadIdx.x, w = t >> 6, ln = t & 63;
  int c = ln & 15, qd = ln >> 4;
  int hh = blockIdx.y, ks = blockIdx.z;
  int q0 = blockIdx.x * 64 + w * 16;
  union { uint4 u; bf16x8 v; } qf;
  qf.u = *(const uint4*)(qb + (q0 + c) * HH + hh * HDIM + qd * 8);
  f32x4 o0 = {0.f,0.f,0.f,0.f}, o1 = {0.f,0.f,0.f,0.f};
  float denp = 0.f;
  const float scale = 0.17677669529663687f;
  unsigned short* P = &Pl[w][0];
  const unsigned short* vrow0 = vt + (hh * HDIM + c) * NN;
  const unsigned short* vrow1 = vt + (hh * HDIM + 16 + c) * NN;
  for (int k0 = ks * (NN / KS); k0 < (ks + 1) * (NN / KS); k0 += 32){
    #pragma unroll
    for (int tt = 0; tt < 2; tt++){
      union { uint4 u; bf16x8 v; } kf;
      kf.u = *(const uint4*)(kb + (k0 + tt * 16 + c) * HH + hh * HDIM + qd * 8);
      f32x4 s = {0.f,0.f,0.f,0.f};
      s = __builtin_amdgcn_mfma_f32_16x16x32_bf16(kf.v, qf.v, s, 0, 0, 0);
      float e0 = expf(s[0] * scale), e1 = expf(s[1] * scale);
      float e2 = expf(s[2] * scale), e3 = expf(s[3] * scale);
      denp += (e0 + e1) + (e2 + e3);
      unsigned p01 = (unsigned)f2bf(e0) | ((unsigned)f2bf(e1) << 16);
      unsigned p23 = (unsigned)f2bf(e2) | ((unsigned)f2bf(e3) << 16);
      *(unsigned*)(P + c * PSTR + tt * 16 + qd * 4)     = p01;
      *(unsigned*)(P + c * PSTR + tt * 16 + qd * 4 + 2) = p23;
    }
    union { uint4 u; bf16x8 v; } af, b0, b1;
    af.u = *(const uint4*)(P + c * PSTR + qd * 8);
    b0.u = *(const uint4*)(vrow0 + k0 + qd * 8);
    b1.u = *(const uint4*)(vrow1 + k0 + qd * 8);
    o0 = __builtin_amdgcn_mfma_f32_16x16x32_bf16(af.v, b0.v, o0, 0, 0, 0);
    o1 = __builtin_amdgcn_mfma_f32_16x16x32_bf16(af.v, b1.v, o1, 0, 0, 0);
  }
  denp += __shfl_xor(denp, 16);
  denp += __shfl_xor(denp, 32);
  if (qd == 0) pden[((q0 + c) * NHEADS + hh) * KS + ks] = denp;
  #pragma unroll
  for (int r = 0; r < 4; r++){
    int qn = q0 + qd * 4 + r;
    int pi = (qn * NHEADS + hh) * KS + ks;
    pacc[pi * HDIM + c]      = o0[r];
    pacc[pi * HDIM + 16 + c] = o1[r];
  }
}

__global__ void k_attn_comb(const float* __restrict__ pden, const float* __restrict__ pacc,
                            unsigned short* __restrict__ aob){
  int n = blockIdx.x, j = threadIdx.x;
  int hh = j >> 5, d = j & 31;
  float ds = 0.0f, as = 0.0f;
  #pragma unroll
  for (int ks = 0; ks < KS; ks++){
    int pi = (n * NHEADS + hh) * KS + ks;
    ds += pden[pi];
    as += pacc[pi * HDIM + d];
  }
  aob[n * HH + j] = f2bf(as / ds);
}

__global__ void k_resln(const float* __restrict__ proj, const float* __restrict__ g,
                        const float* __restrict__ b, float* __restrict__ h,
                        unsigned short* __restrict__ hb){
  __shared__ float red[128];
  int n = blockIdx.x, j = threadIdx.x;
  float val = h[n * HH + j] + proj[n * HH + j];
  float mu = block_sum128(val, red) * (1.0f / HH);
  float dd = val - mu;
  float var = block_sum128(dd * dd, red) * (1.0f / HH);
  float r = dd * rsqrtf(var + 1e-5f) * g[j] + b[j];
  h[n * HH + j] = r;
  hb[n * HH + j] = f2bf(r);
}

// ---------------- edge heads via MFMA (col-split waves) ----------------
// Block: 64 edges, 4 waves; wave w owns output cols [64w, 64w+64) (4 col-tiles),
// all 64 edges (4 row-tiles). Per ks: 4 A-frags (LDS) + 4 B-frags (global) -> 16 MFMA.
// W2 reduction: per-lane over its 4 cols, shfl over lm, LDS float atomics across quads/waves.
__global__ __launch_bounds__(256) void k_edge_mfma(
    const unsigned short* __restrict__ hb, const unsigned short* __restrict__ eab,
    const int* __restrict__ ei, const unsigned short* __restrict__ wb,
    const float* __restrict__ mvb1, const float* __restrict__ frb1,
    const float* __restrict__ mvW2, const float* __restrict__ mvb2,
    const float* __restrict__ frW2, const float* __restrict__ frb2,
    float* __restrict__ out){
  __shared__ __align__(16) unsigned short As[64 * KPAD];
  __shared__ float am[64], a0[64], a1[64];
  int t = threadIdx.x;
  int e0 = blockIdx.x * 64;
  if (t < 64){ am[t] = 0.f; a0[t] = 0.f; a1[t] = 0.f; }
  {
    int el = t >> 2, p = t & 3;
    int e = e0 + el;
    int node = (p < 2) ? ei[e] : ei[EE + e];
    int half = p & 1;
    const uint4* srcp = (const uint4*)(hb + node * HH + half * 64);
    uint4* dstp = (uint4*)(As + el * KPAD + (p >> 1) * 128 + half * 64);
    #pragma unroll
    for (int i = 0; i < 8; i++) dstp[i] = srcp[i];
    if (p == 0){
      unsigned short* tail = As + el * KPAD + 256;
      tail[0] = eab[e * 4];     tail[1] = eab[e * 4 + 1];
      tail[2] = eab[e * 4 + 2]; tail[3] = eab[e * 4 + 3];
      #pragma unroll
      for (int i = 4; i < KPAD - 256; i++) tail[i] = 0;
    }
  }
  int ln = t & 63, w = t >> 6, lm = ln & 15, quad = ln >> 4;
  const unsigned short* bbase = wb + (w * 64 + lm) * KPAD + quad * 8;
  f32x4 acc[4][4];
  #pragma unroll
  for (int rt = 0; rt < 4; rt++)
    #pragma unroll
    for (int t2 = 0; t2 < 4; t2++) acc[rt][t2] = (f32x4){0.f, 0.f, 0.f, 0.f};
  __syncthreads();
  for (int ks = 0; ks < 9; ks++){
    union { uint4 u; bf16x8 v; } bf[4], af[4];
    #pragma unroll
    for (int t2 = 0; t2 < 4; t2++) bf[t2].u = *(const uint4*)(bbase + t2 * 16 * KPAD + ks * 32);
    #pragma unroll
    for (int rt = 0; rt < 4; rt++) af[rt].u = *(const uint4*)(As + (16 * rt + lm) * KPAD + quad * 8 + ks * 32);
    #pragma unroll
    for (int rt = 0; rt < 4; rt++)
      #pragma unroll
      for (int t2 = 0; t2 < 4; t2++)
        acc[rt][t2] = __builtin_amdgcn_mfma_f32_16x16x32_bf16(af[rt].v, bf[t2].v, acc[rt][t2], 0, 0, 0);
  }
  // epilogue: rows 16rt + 4quad + r; cols 64w + 16t2 + lm
  if (w < 2){
    #pragma unroll
    for (int rt = 0; rt < 4; rt++){
      #pragma unroll
      for (int r = 0; r < 4; r++){
        float s = 0.f;
        #pragma unroll
        for (int t2 = 0; t2 < 4; t2++){
          int n = w * 64 + t2 * 16 + lm;
          s += gelu_f(acc[rt][t2][r] + mvb1[n]) * mvW2[n];
        }
        #pragma unroll
        for (int d = 1; d < 16; d <<= 1) s += __shfl_xor(s, d);
        if (lm == 0) atomicAdd(&am[16 * rt + 4 * quad + r], s);
      }
    }
  } else {
    #pragma unroll
    for (int rt = 0; rt < 4; rt++){
      #pragma unroll
      for (int r = 0; r < 4; r++){
        float s0 = 0.f, s1 = 0.f;
        #pragma unroll
        for (int t2 = 0; t2 < 4; t2++){
          int n = (w - 2) * 64 + t2 * 16 + lm;
          float g = gelu_f(acc[rt][t2][r] + frb1[n]);
          s0 += g * frW2[n];
          s1 += g * frW2[128 + n];
        }
        #pragma unroll
        for (int d = 1; d < 16; d <<= 1){ s0 += __shfl_xor(s0, d); s1 += __shfl_xor(s1, d); }
        if (lm == 0){
          atomicAdd(&a0[16 * rt + 4 * quad + r], s0);
          atomicAdd(&a1[16 * rt + 4 * quad + r], s1);
        }
      }
    }
  }
  __syncthreads();
  if (t < 64){
    int e = e0 + t;
    out[e]          = am[t] + mvb2[0];
    out[EE + e]     = softplus_f(a0[t] + frb2[0]) + 1e-4f;
    out[2 * EE + e] = softplus_f(a1[t] + frb2[1]) + 1e-4f;
  }
}

// ---------------- value head ----------------
__global__ void k_pool(const float* __restrict__ h, const unsigned char* __restrict__ mask,
                       float* __restrict__ gsum, float* __restrict__ msum, float* __restrict__ mcnt){
  int bb = blockIdx.x, j = threadIdx.x;
  float ga = 0.0f, ma = 0.0f;
  int n0 = bb * 32;
  for (int i = 0; i < 32; i++){
    int n = n0 + i;
    float v = h[n * HH + j];
    ga += v;
    if (mask[n]) ma += v;
  }
  atomicAdd(&gsum[j], ga);
  atomicAdd(&msum[j], ma);
  if (j == 0){
    float c = 0.0f;
    for (int i = 0; i < 32; i++) c += mask[n0 + i] ? 1.0f : 0.0f;
    atomicAdd(mcnt, c);
  }
}

__global__ void k_value(const float* __restrict__ gsum, const float* __restrict__ msum,
                        const float* __restrict__ mcnt,
                        const float* __restrict__ W1, const float* __restrict__ b1,
                        const float* __restrict__ W2, const float* __restrict__ b2,
                        float* __restrict__ out_val){
  __shared__ float red[128];
  __shared__ float vin[256];
  int j = threadIdx.x;
  float gp = gsum[j] * (1.0f / NN);
  float as = msum[j] * (1.0f / NN);
  float ac = fmaxf(mcnt[0] * (1.0f / NN), 1e-6f);
  vin[j] = gp; vin[HH + j] = as / ac;
  __syncthreads();
  float acc = b1[j];
  const float* w = &W1[j * 256];
  #pragma unroll 4
  for (int k = 0; k < 256; k++) acc += vin[k] * w[k];
  float hv = gelu_f(acc) * W2[j];
  float s = block_sum128(hv, red);
  if (j == 0) out_val[0] = s + b2[0];
}

extern "C" void kernel_launch(void* const* d_in, const int* in_sizes, int n_in,
                              void* d_out, int out_size, void* d_ws, size_t ws_size,
                              hipStream_t stream){
  (void)in_sizes; (void)n_in; (void)out_size; (void)ws_size;
  const float* x        = (const float*)d_in[0];
  const int*   ei       = (const int*)d_in[1];
  const float* ea       = (const float*)d_in[2];
  const float* u        = (const float*)d_in[3];
  const unsigned char* mask = (const unsigned char*)d_in[4];
  const float* tiles    = (const float*)d_in[5];
  const float* tf       = (const float*)d_in[7];
  const float* ne_W  = (const float*)d_in[8];
  const float* ne_b  = (const float*)d_in[9];
  const float* ne_g  = (const float*)d_in[10];
  const float* ne_be = (const float*)d_in[11];
  const float* ge_W  = (const float*)d_in[12];
  const float* ge_b  = (const float*)d_in[13];
  const float* ge_g  = (const float*)d_in[14];
  const float* ge_be = (const float*)d_in[15];
  const float* gru_Wih = (const float*)d_in[16];
  const float* gru_bih = (const float*)d_in[17];
  const float* gru_Whh = (const float*)d_in[18];
  const float* gru_bhh = (const float*)d_in[19];
  const float* gat_Wl  = (const float*)d_in[20];
  const float* gat_bl  = (const float*)d_in[21];
  const float* gat_Wr  = (const float*)d_in[22];
  const float* gat_br  = (const float*)d_in[23];
  const float* gat_We  = (const float*)d_in[24];
  const float* gat_att = (const float*)d_in[25];
  const float* gat_bias= (const float*)d_in[26];
  const float* ln_g    = (const float*)d_in[27];
  const float* ln_b    = (const float*)d_in[28];
  const float* attn_Win = (const float*)d_in[29];
  const float* attn_bin = (const float*)d_in[30];
  const float* attn_Wout= (const float*)d_in[31];
  const float* attn_bout= (const float*)d_in[32];
  const float* lng_g    = (const float*)d_in[33];
  const float* lng_b    = (const float*)d_in[34];
  const float* mv_W1 = (const float*)d_in[35];
  const float* mv_b1 = (const float*)d_in[36];
  const float* mv_W2 = (const float*)d_in[37];
  const float* mv_b2 = (const float*)d_in[38];
  const float* fr_W1 = (const float*)d_in[39];
  const float* fr_b1 = (const float*)d_in[40];
  const float* fr_W2 = (const float*)d_in[41];
  const float* fr_b2 = (const float*)d_in[42];
  const float* vl_W1 = (const float*)d_in[43];
  const float* vl_b1 = (const float*)d_in[44];
  const float* vl_W2 = (const float*)d_in[45];
  const float* vl_b2 = (const float*)d_in[46];

  // ---- workspace layout (f32 elem offsets), total 5638592 f32 = 22.55 MB ----
  float* ws = (float*)d_ws;
  float* h      = ws;                         // 524288
  float* xlr    = ws + 524288;                // 1048576 ([N][256])
  unsigned short* hb     = (unsigned short*)(ws + 1572864);  // NN*HH bf16
  unsigned short* tilesb = (unsigned short*)(ws + 1835008);  // NN*HH bf16
  unsigned short* wbuf   = (unsigned short*)(ws + 2097152);  // 294912 bf16
  unsigned short* Wihb  = wbuf;
  unsigned short* Whhb  = wbuf + 49152;
  unsigned short* Wlrb  = wbuf + 98304;   // [L][256][128]
  unsigned short* Winb  = wbuf + 229376;
  unsigned short* Woutb = wbuf + 278528;
  float* blrc   = ws + 2244608;               // [L][256]
  float* ue     = ws + 2245632;               // 128
  float* gsum   = ws + 2245760;               // 128
  float* msum   = ws + 2245888;               // 128
  float* mcnt   = ws + 2246016;               // 1 (+pad)
  int*   cnt    = (int*)(ws + 2246032);       // 4096
  int*   off    = cnt + NN;                   // 4097
  int*   cur    = off + NN + 1;               // 4096
  int*   eid    = cur + NN;                   // 65536 (ends 2323857)
  unsigned short* eab = (unsigned short*)(ws + 2323904);  // EE*4 bf16 (131072 f32)
  unsigned short* wbE = (unsigned short*)(ws + 2454976);  // 256*KPAD bf16 (37888 f32)
  float* S      = ws + 2492864;               // 3145728 scratch (multi-phase)
  // GRU phase:
  float* gi = S;                  // [N][384]
  float* gh = S + 1572864;        // [N][384]
  // GAT phase:
  float* ex = S;                  // [E][4]
  // attention phase:
  float* qkvf = S;                                      // [N][384]
  unsigned short* qb = (unsigned short*)(S + 1572864);
  unsigned short* kb = (unsigned short*)(S + 1835008);
  unsigned short* vt = (unsigned short*)(S + 2097152);
  float* pacc = S;                                      // 1048576 (after qkvf dead)
  float* pden = S + 1048576;                            // 32768
  unsigned short* aob = (unsigned short*)(S + 1081344); // NN*HH bf16
  float* aoproj = S + 1572864;                          // [N][128] (after qb dead)

  float* out       = (float*)d_out;
  float* out_val   = out + 3 * EE;
  float* out_tiles = out + 3 * EE + 1;

  // CSR of incoming edges
  hipMemsetAsync(cnt, 0, NN * sizeof(int), stream);
  k_hist   <<<EE / 256, 256, 0, stream>>>(ei, cnt);
  k_scan   <<<1, 256, 0, stream>>>(cnt, off, cur);
  k_scatter<<<EE / 256, 256, 0, stream>>>(ei, cur, eid);

  // one-shot bf16 prep (weights, tiles, edge_attr, edge-head W1)
  k_wprep<<<(1158144 + 255) / 256, 256, 0, stream>>>(gru_Wih, gru_Whh, gat_Wl, gat_Wr,
                                                     attn_Win, attn_Wout, tiles,
                                                     gat_bl, gat_br, ea, mv_W1, fr_W1,
                                                     wbuf, tilesb, blrc, wbE, eab);

  // encoders
  k_ue      <<<1, 128, 0, stream>>>(u, ge_W, ge_b, ge_g, ge_be, ue);
  k_node_enc<<<NN, 128, 0, stream>>>(x, tf, ne_W, ne_b, ne_g, ne_be, ue, h, hb);

  // GRU via MFMA
  { dim3 g(NN / 64, 3);
    k_lin<384><<<g, 256, 0, stream>>>(hb, Wihb, gru_bih, gi);
    k_lin<384><<<g, 256, 0, stream>>>(tilesb, Whhb, gru_bhh, gh); }
  k_gru_comb<<<NN * HH / 256, 256, 0, stream>>>(gi, gh, tiles, h, hb, out_tiles);

  // GATv2 stack
  for (int l = 0; l < NLAYERS; l++){
    { dim3 g(NN / 64, 2);
      k_lin<256><<<g, 256, 0, stream>>>(hb, Wlrb + l * 32768, blrc + l * 256, xlr); }
    k_score<<<EE / 16, 256, 0, stream>>>(ei, ea, xlr,
                                         gat_We + l * HH * EFEAT,
                                         gat_att + l * NHEADS * HDIM, ex);
    k_aggln<<<NN, 128, 0, stream>>>(xlr, ex, off, eid, ei,
                                    gat_bias + l * HH, ln_g + l * HH, ln_b + l * HH, h, hb);
  }

  // global attention
  { dim3 g(NN / 64, 3);
    k_lin<384><<<g, 256, 0, stream>>>(hb, Winb, attn_bin, qkvf); }
  k_qkv_post<<<NN / 64, 256, 0, stream>>>(qkvf, qb, kb, vt);
  { dim3 gattn(NN / 64, NHEADS, KS);
    k_attn_flash<<<gattn, 256, 0, stream>>>(qb, kb, vt, pden, pacc); }
  k_attn_comb<<<NN, 128, 0, stream>>>(pden, pacc, aob);
  { dim3 g(NN / 64, 1);
    k_lin<128><<<g, 256, 0, stream>>>(aob, Woutb, attn_bout, aoproj); }
  k_resln<<<NN, 128, 0, stream>>>(aoproj, lng_g, lng_b, h, hb);

  // edge heads (bf16 MFMA, col-split waves)
  k_edge_mfma<<<EE / 64, 256, 0, stream>>>(hb, eab, ei, wbE, mv_b1, fr_b1,
                                           mv_W2, mv_b2, fr_W2, fr_b2, out);

  // value head
  hipMemsetAsync(gsum, 0, 257 * sizeof(float), stream);
  k_pool <<<128, 128, 0, stream>>>(h, mask, gsum, msum, mcnt);
  k_value<<<1, 128, 0, stream>>>(gsum, msum, mcnt, vl_W1, vl_b1, vl_W2, vl_b2, out_val);
}